// Round 1
// baseline (700.969 us; speedup 1.0000x reference)
//
#include <hip/hip_runtime.h>
#include <hip/hip_bf16.h>
#include <math.h>

#define Bz 16
#define Nz 1024
#define Mz 4
#define Dz 128
#define Hz 4
#define VOCABz 32000
#define CAP 128

// ---------------- CSR build: mask[b,n,m] = adj>0 || (m==n && n>=kb_len+conv_len) ----------
__global__ void k_csr(const float* __restrict__ adj, const int* __restrict__ kb_len,
                      const int* __restrict__ conv_len, int* __restrict__ idx,
                      int* __restrict__ cnt) {
    int row = blockIdx.x;                 // b*N + n
    int b = row >> 10, n = row & 1023;
    __shared__ int scnt;
    if (threadIdx.x == 0) scnt = 0;
    __syncthreads();
    int ctx = kb_len[b] + conv_len[b];
    const float* arow = adj + (size_t)row * Nz;
    for (int m = threadIdx.x; m < Nz; m += blockDim.x) {
        bool on = (arow[m] > 0.f) || (m == n && n >= ctx);
        if (on) {
            int p = atomicAdd(&scnt, 1);
            if (p < CAP) idx[(size_t)row * CAP + p] = m;
        }
    }
    __syncthreads();
    if (threadIdx.x == 0) cnt[row] = scnt < CAP ? scnt : CAP;
}

// ---------------- embed: x[b,n,d] = sum_m emb_k[story[b,n,m],d] (+ dh scatter) ------------
__global__ void k_embed(const int* __restrict__ story, const float* __restrict__ emb_k,
                        const float* __restrict__ dh, const int* __restrict__ kb_len,
                        const int* __restrict__ conv_len, float* __restrict__ x) {
    int row = blockIdx.x;                 // b*N + n
    int b = row >> 10, n = row & 1023;
    int d = threadIdx.x;                  // 128
    const int* st = story + (size_t)row * Mz;
    int s0 = st[0], s1 = st[1], s2 = st[2], s3 = st[3];
    float acc = emb_k[(size_t)s0 * Dz + d] + emb_k[(size_t)s1 * Dz + d]
              + emb_k[(size_t)s2 * Dz + d] + emb_k[(size_t)s3 * Dz + d];
    int rel = n - (kb_len[b] - 1);
    if (rel >= 0 && rel < conv_len[b]) acc += dh[((size_t)b * Nz + rel) * Dz + d];
    x[(size_t)row * Dz + d] = acc;
}

// ---------------- Wh GEMM: Wh[row, h*128+e] = sum_d x[row,d] * W[h,d,e] -------------------
// grid (512, 4), block 256. LDS-tiled, d split into 2 chunks of 64 to stay <64KB LDS.
#define GR 32
__global__ __launch_bounds__(256) void k_wh(const float* __restrict__ x,
                                            const float* __restrict__ W,
                                            float* __restrict__ Wh) {
    int h = blockIdx.y;
    int row0 = blockIdx.x * GR;
    int t = threadIdx.x;
    __shared__ float WsT[128 * 68];       // [e][dloc], stride 68
    __shared__ float xt[GR * 64];         // [r][dloc]
    int cg = t & 31;                      // col group: cols c0..c0+3
    int rg = t >> 5;                      // row group: rows r0..r0+3
    int c0 = cg * 4, r0 = rg * 4;
    float acc[4][4];
#pragma unroll
    for (int i = 0; i < 4; i++)
#pragma unroll
        for (int j = 0; j < 4; j++) acc[i][j] = 0.f;

    for (int ph = 0; ph < 2; ph++) {
        int dbase = ph * 64;
        for (int i = t; i < 128 * 64; i += 256) {
            int dloc = i >> 7, e = i & 127;
            WsT[e * 68 + dloc] = W[(size_t)h * Dz * Dz + (size_t)(dbase + dloc) * Dz + e];
        }
        for (int i = t; i < GR * 64; i += 256) {
            int r = i >> 6, dloc = i & 63;
            xt[r * 64 + dloc] = x[(size_t)(row0 + r) * Dz + dbase + dloc];
        }
        __syncthreads();
#pragma unroll 4
        for (int dd = 0; dd < 64; dd += 4) {
            float4 xv[4], wv[4];
#pragma unroll
            for (int i = 0; i < 4; i++) xv[i] = *(const float4*)&xt[(r0 + i) * 64 + dd];
#pragma unroll
            for (int j = 0; j < 4; j++) wv[j] = *(const float4*)&WsT[(c0 + j) * 68 + dd];
#pragma unroll
            for (int i = 0; i < 4; i++)
#pragma unroll
                for (int j = 0; j < 4; j++)
                    acc[i][j] += xv[i].x * wv[j].x + xv[i].y * wv[j].y
                               + xv[i].z * wv[j].z + xv[i].w * wv[j].w;
        }
        __syncthreads();
    }
#pragma unroll
    for (int i = 0; i < 4; i++) {
        float4 v = make_float4(acc[i][0], acc[i][1], acc[i][2], acc[i][3]);
        *(float4*)&Wh[(size_t)(row0 + r0 + i) * (Hz * Dz) + h * Dz + c0] = v;
    }
}

// ---------------- f1/f2: per (row,h): dots of Wh row with a[h,:128] and a[h,128:] ---------
__global__ void k_f(const float* __restrict__ Wh, const float* __restrict__ a,
                    float* __restrict__ f1, float* __restrict__ f2) {
    int row = blockIdx.x;
    int h = threadIdx.x >> 6;             // wave index = head
    int lane = threadIdx.x & 63;
    const float* wr = Wh + (size_t)row * (Hz * Dz) + h * Dz;
    float w0 = wr[lane], w1 = wr[lane + 64];
    const float* ah = a + h * 2 * Dz;
    float s1 = w0 * ah[lane] + w1 * ah[lane + 64];
    float s2 = w0 * ah[Dz + lane] + w1 * ah[Dz + lane + 64];
#pragma unroll
    for (int off = 32; off; off >>= 1) {
        s1 += __shfl_down(s1, off);
        s2 += __shfl_down(s2, off);
    }
    if (lane == 0) {
        f1[(size_t)row * Hz + h] = s1;
        f2[(size_t)row * Hz + h] = s2;
    }
}

// ---------------- sparse GAT attention + head-mean aggregation ----------------------------
__global__ __launch_bounds__(128) void k_attn(const float* __restrict__ Wh,
                                              const float* __restrict__ f1,
                                              const float* __restrict__ f2,
                                              const int* __restrict__ idx,
                                              const int* __restrict__ cnt,
                                              float* __restrict__ G) {
    int row = blockIdx.x;                 // b*N + n
    int b = row >> 10;
    int t = threadIdx.x;                  // 128
    __shared__ int sidx[CAP];
    __shared__ float sat[Hz][CAP];
    __shared__ float sf1[Hz];
    int deg = cnt[row];
    if (t < Hz) sf1[t] = f1[(size_t)row * Hz + t];
    __syncthreads();
    if (deg > 0) {
        if (t < deg) {
            int m = idx[(size_t)row * CAP + t];
            sidx[t] = m;
            const float* f2m = f2 + ((size_t)(b << 10) + m) * Hz;
#pragma unroll
            for (int h = 0; h < Hz; h++) {
                float e = sf1[h] + f2m[h];
                e = e >= 0.f ? e : 0.2f * e;
                sat[h][t] = e;
            }
        }
        __syncthreads();
        if (t < Hz) {                     // per-head softmax over the deg entries
            float mx = -1e30f;
            for (int j = 0; j < deg; j++) mx = fmaxf(mx, sat[t][j]);
            float s = 0.f;
            for (int j = 0; j < deg; j++) {
                float v = expf(sat[t][j] - mx);
                sat[t][j] = v;
                s += v;
            }
            float inv = 1.f / s;
            for (int j = 0; j < deg; j++) sat[t][j] *= inv;
        }
        __syncthreads();
        float acc = 0.f;
        for (int j = 0; j < deg; j++) {
            int m = sidx[j];
            const float* wm = Wh + ((size_t)(b << 10) + m) * (Hz * Dz);
            acc += sat[0][j] * wm[t] + sat[1][j] * wm[Dz + t]
                 + sat[2][j] * wm[2 * Dz + t] + sat[3][j] * wm[3 * Dz + t];
        }
        G[(size_t)row * Dz + t] = acc * (1.f / Hz);
    } else {
        // all-masked row: softmax of constant -9e15 = uniform 1/N over ALL m (JAX semantics)
        float acc = 0.f;
        const float* wb = Wh + ((size_t)(b << 10)) * (Hz * Dz);
        for (int m = 0; m < Nz; m++) {
            const float* wm = wb + (size_t)m * Hz * Dz;
            acc += wm[t] + wm[Dz + t] + wm[2 * Dz + t] + wm[3 * Dz + t];
        }
        G[(size_t)row * Dz + t] = acc * (1.f / (Hz * Nz));
    }
}

// ---------------- hop pieces --------------------------------------------------------------
__global__ void k_uinit(const float* __restrict__ hidden, float* __restrict__ u) {
    u[blockIdx.x * Dz + threadIdx.x] = hidden[blockIdx.x * Dz + threadIdx.x];
}

__global__ void k_logits(const float* __restrict__ G, const float* __restrict__ u,
                         float* __restrict__ logits) {
    int row = blockIdx.x * 4 + (threadIdx.x >> 6);
    int lane = threadIdx.x & 63;
    int b = row >> 10;
    const float* g = G + (size_t)row * Dz;
    const float* ub = u + b * Dz;
    float s = g[lane] * ub[lane] + g[lane + 64] * ub[lane + 64];
#pragma unroll
    for (int off = 32; off; off >>= 1) s += __shfl_down(s, off);
    if (lane == 0) logits[row] = s;
}

__global__ void k_softmax(const float* __restrict__ logits, float* __restrict__ p) {
    int b = blockIdx.x;
    int t = threadIdx.x;                  // 256
    __shared__ float sh[16];
    const float* l = logits + (size_t)b * Nz;
    float mx = -1e30f;
    for (int i = t; i < Nz; i += 256) mx = fmaxf(mx, l[i]);
#pragma unroll
    for (int off = 32; off; off >>= 1) mx = fmaxf(mx, __shfl_down(mx, off));
    if ((t & 63) == 0) sh[t >> 6] = mx;
    __syncthreads();
    if (t == 0) {
        float m = sh[0];
        for (int i = 1; i < 4; i++) m = fmaxf(m, sh[i]);
        sh[0] = m;
    }
    __syncthreads();
    mx = sh[0];
    float s = 0.f;
    for (int i = t; i < Nz; i += 256) s += expf(l[i] - mx);
#pragma unroll
    for (int off = 32; off; off >>= 1) s += __shfl_down(s, off);
    if ((t & 63) == 0) sh[8 + (t >> 6)] = s;
    __syncthreads();
    if (t == 0) {
        float ss = 0.f;
        for (int i = 0; i < 4; i++) ss += sh[8 + i];
        sh[12] = ss;
    }
    __syncthreads();
    float inv = 1.f / sh[12];
    for (int i = t; i < Nz; i += 256) p[(size_t)b * Nz + i] = expf(l[i] - mx) * inv;
}

// u[b,d] += sum_n G[b,n,d] * p[b,n]; grid = B*8 chunks of 128 n
__global__ void k_uupd(const float* __restrict__ G, const float* __restrict__ p,
                       float* __restrict__ u) {
    int b = blockIdx.x >> 3;
    int c = blockIdx.x & 7;
    int d = threadIdx.x;                  // 128
    int n0 = c * 128;
    const float* g = G + ((size_t)b * Nz + n0) * Dz + d;
    const float* pb = p + (size_t)b * Nz + n0;
    float acc = 0.f;
#pragma unroll 4
    for (int j = 0; j < 128; j++) acc += g[(size_t)j * Dz] * pb[j];
    atomicAdd(&u[b * Dz + d], acc);
}

__global__ void k_final(const float* __restrict__ logits, const float* __restrict__ u,
                        float* __restrict__ out) {
    int i = blockIdx.x * 256 + threadIdx.x;
    if (i < Bz * Nz) {
        float l = logits[i];
        out[i] = 1.f / (1.f + expf(-l));
        out[Bz * Nz + Bz * Dz + i] = l;
    }
    if (i < Bz * Dz) out[Bz * Nz + i] = u[i];
}

// ---------------- host ---------------------------------------------------------------------
extern "C" void kernel_launch(void* const* d_in, const int* in_sizes, int n_in,
                              void* d_out, int out_size, void* d_ws, size_t ws_size,
                              hipStream_t stream) {
    const int*   story    = (const int*)d_in[0];
    const int*   kb_len   = (const int*)d_in[1];
    const int*   conv_len = (const int*)d_in[2];
    const float* hidden   = (const float*)d_in[3];
    const float* dh       = (const float*)d_in[4];
    const float* adj      = (const float*)d_in[5];
    const float* emb      = (const float*)d_in[6];
    const float* gat_W    = (const float*)d_in[7];
    const float* gat_a    = (const float*)d_in[8];
    float* out = (float*)d_out;

    char* w = (char*)d_ws;
    auto alloc = [&](size_t bytes) {
        char* pp = w;
        w += (bytes + 255) & ~(size_t)255;
        return pp;
    };
    const size_t BN = (size_t)Bz * Nz;
    int*   idx    = (int*)  alloc(BN * CAP * 4);
    int*   cnt    = (int*)  alloc(BN * 4);
    float* x      = (float*)alloc(BN * Dz * 4);
    float* Wh     = (float*)alloc(BN * Hz * Dz * 4);
    float* f1     = (float*)alloc(BN * Hz * 4);
    float* f2     = (float*)alloc(BN * Hz * 4);
    float* GA     = (float*)alloc(BN * Dz * 4);
    float* GB     = (float*)alloc(BN * Dz * 4);
    float* logits = (float*)alloc(BN * 4);
    float* p      = (float*)alloc(BN * 4);
    float* u      = (float*)alloc((size_t)Bz * Dz * 4);

    k_csr<<<BN, 256, 0, stream>>>(adj, kb_len, conv_len, idx, cnt);
    k_uinit<<<Bz, Dz, 0, stream>>>(hidden, u);

    auto computeG = [&](int k, float* G) {
        k_embed<<<BN, Dz, 0, stream>>>(story, emb + (size_t)k * VOCABz * Dz, dh, kb_len,
                                       conv_len, x);
        dim3 grid(BN / GR, Hz);
        k_wh<<<grid, 256, 0, stream>>>(x, gat_W + (size_t)k * Hz * Dz * Dz, Wh);
        k_f<<<BN, 256, 0, stream>>>(Wh, gat_a + (size_t)k * Hz * 2 * Dz, f1, f2);
        k_attn<<<BN, 128, 0, stream>>>(Wh, f1, f2, idx, cnt, G);
    };

    computeG(0, GA);
    computeG(1, GB);
    // hop 0: A=G0 (GA), Cm=G1 (GB)
    k_logits<<<BN / 4, 256, 0, stream>>>(GA, u, logits);
    k_softmax<<<Bz, 256, 0, stream>>>(logits, p);
    k_uupd<<<Bz * 8, Dz, 0, stream>>>(GB, p, u);
    computeG(2, GA);
    // hop 1: A=G1 (GB), Cm=G2 (GA)
    k_logits<<<BN / 4, 256, 0, stream>>>(GB, u, logits);
    k_softmax<<<Bz, 256, 0, stream>>>(logits, p);
    k_uupd<<<Bz * 8, Dz, 0, stream>>>(GA, p, u);
    computeG(3, GB);
    // hop 2: A=G2 (GA), Cm=G3 (GB)
    k_logits<<<BN / 4, 256, 0, stream>>>(GA, u, logits);
    k_softmax<<<Bz, 256, 0, stream>>>(logits, p);
    k_uupd<<<Bz * 8, Dz, 0, stream>>>(GB, p, u);

    k_final<<<(Bz * Nz + 255) / 256, 256, 0, stream>>>(logits, u, out);
}

// Round 2
// 577.264 us; speedup vs baseline: 1.2143x; 1.2143x over previous
//
#include <hip/hip_runtime.h>
#include <hip/hip_bf16.h>
#include <math.h>

#define Bz 16
#define Nz 1024
#define Mz 4
#define Dz 128
#define Hz 4
#define VOCABz 32000
#define CAP 128

typedef __attribute__((ext_vector_type(8))) short bf16x8;
typedef __attribute__((ext_vector_type(4))) float f32x4;

__device__ inline unsigned short rne_bf16(float x) {
    unsigned u = __float_as_uint(x);
    unsigned r = (u + 0x7FFFu + ((u >> 16) & 1u)) >> 16;
    return (unsigned short)r;
}
__device__ inline float bf16_to_f(unsigned short h) {
    return __uint_as_float(((unsigned)h) << 16);
}

// ---------------- CSR build: mask[b,n,m] = adj>0 || (m==n && n>=kb_len+conv_len) ----------
__global__ void k_csr(const float* __restrict__ adj, const int* __restrict__ kb_len,
                      const int* __restrict__ conv_len, int* __restrict__ idx,
                      int* __restrict__ cnt) {
    int row = blockIdx.x;                 // b*N + n
    int b = row >> 10, n = row & 1023;
    __shared__ int scnt;
    if (threadIdx.x == 0) scnt = 0;
    __syncthreads();
    int ctx = kb_len[b] + conv_len[b];
    const float* arow = adj + (size_t)row * Nz;
    for (int m = threadIdx.x; m < Nz; m += blockDim.x) {
        bool on = (arow[m] > 0.f) || (m == n && n >= ctx);
        if (on) {
            int p = atomicAdd(&scnt, 1);
            if (p < CAP) idx[(size_t)row * CAP + p] = m;
        }
    }
    __syncthreads();
    if (threadIdx.x == 0) cnt[row] = scnt < CAP ? scnt : CAP;
}

// ---------------- W pre-split+transpose: WT[k][h][e][d] hi/lo bf16 ------------------------
// in: gat_W[(k*4+h)*128 + d]*128 + e ; out index i = ((k*4+h)*128 + e)*128 + d
__global__ void k_wsplit(const float* __restrict__ gat_W, unsigned short* __restrict__ wthi,
                         unsigned short* __restrict__ wtlo) {
    int i = blockIdx.x * 256 + threadIdx.x;       // 4*4*128*128 = 262144
    int d = i & 127;
    int e = (i >> 7) & 127;
    int kh = i >> 14;
    float v = gat_W[((size_t)kh * 128 + d) * 128 + e];
    unsigned short h = rne_bf16(v);
    float lo = v - bf16_to_f(h);
    wthi[i] = h;
    wtlo[i] = rne_bf16(lo);
}

// ---------------- embed: x = sum emb rows (+ dh scatter), split to bf16 hi/lo -------------
__global__ void k_embed(const int* __restrict__ story, const float* __restrict__ emb_k,
                        const float* __restrict__ dh, const int* __restrict__ kb_len,
                        const int* __restrict__ conv_len, unsigned short* __restrict__ xhi,
                        unsigned short* __restrict__ xlo, float* __restrict__ f1,
                        float* __restrict__ f2) {
    int row = blockIdx.x;                 // b*N + n
    int b = row >> 10, n = row & 1023;
    int d = threadIdx.x;                  // 128
    const int* st = story + (size_t)row * Mz;
    int s0 = st[0], s1 = st[1], s2 = st[2], s3 = st[3];
    float acc = emb_k[(size_t)s0 * Dz + d] + emb_k[(size_t)s1 * Dz + d]
              + emb_k[(size_t)s2 * Dz + d] + emb_k[(size_t)s3 * Dz + d];
    int rel = n - (kb_len[b] - 1);
    if (rel >= 0 && rel < conv_len[b]) acc += dh[((size_t)b * Nz + rel) * Dz + d];
    unsigned short hb = rne_bf16(acc);
    float lo = acc - bf16_to_f(hb);
    xhi[(size_t)row * Dz + d] = hb;
    xlo[(size_t)row * Dz + d] = rne_bf16(lo);
    if (d < 4) f1[(size_t)row * Hz + d] = 0.f;
    else if (d < 8) f2[(size_t)row * Hz + (d - 4)] = 0.f;
}

// ---------------- Wh GEMM via bf16x3 MFMA + fused f1/f2 epilogue --------------------------
// C[16384,512] = X[16384,128] @ Wcat[128,512]; block: M=128 rows, N=64 (half of one head).
// grid (8 = h*2+half, 128 rowtiles), 256 threads (4 waves). K in 2 phases of 64.
#define AST 72
__global__ __launch_bounds__(256) void k_whf(const unsigned short* __restrict__ xhi,
                                             const unsigned short* __restrict__ xlo,
                                             const unsigned short* __restrict__ wthi,
                                             const unsigned short* __restrict__ wtlo,
                                             const float* __restrict__ ga,
                                             float* __restrict__ Wh,
                                             float* __restrict__ f1,
                                             float* __restrict__ f2) {
    int h = blockIdx.x >> 1;
    int half = blockIdx.x & 1;
    int e0 = half * 64;
    int row0 = blockIdx.y * 128;
    int t = threadIdx.x;
    int wave = t >> 6, lane = t & 63;
    int quad = lane >> 4, l16 = lane & 15;

    __shared__ unsigned short Ah[128 * AST], Al[128 * AST];   // X tile hi/lo [r][k]
    __shared__ unsigned short Bh[64 * AST], Bl[64 * AST];     // WT tile hi/lo [e][d]

    f32x4 acc[2][4];
#pragma unroll
    for (int mt = 0; mt < 2; mt++)
#pragma unroll
        for (int nt = 0; nt < 4; nt++) acc[mt][nt] = (f32x4)0.f;

    for (int ph = 0; ph < 2; ph++) {
        int kb = ph * 64;
        // stage X: 128 rows x 64 k, 16B chunks
        for (int i = t; i < 1024; i += 256) {
            int r = i >> 3, c = (i & 7) * 8;
            *(uint4*)&Ah[r * AST + c] = *(const uint4*)&xhi[(size_t)(row0 + r) * Dz + kb + c];
            *(uint4*)&Al[r * AST + c] = *(const uint4*)&xlo[(size_t)(row0 + r) * Dz + kb + c];
        }
        // stage WT: 64 e-rows x 64 d
        for (int i = t; i < 512; i += 256) {
            int e = i >> 3, c = (i & 7) * 8;
            size_t src = ((size_t)h * 128 + e0 + e) * 128 + kb + c;
            *(uint4*)&Bh[e * AST + c] = *(const uint4*)&wthi[src];
            *(uint4*)&Bl[e * AST + c] = *(const uint4*)&wtlo[src];
        }
        __syncthreads();
#pragma unroll
        for (int ks = 0; ks < 2; ks++) {
            int ko = ks * 32 + quad * 8;
            bf16x8 ah[2], al[2];
#pragma unroll
            for (int mt = 0; mt < 2; mt++) {
                int r = wave * 32 + mt * 16 + l16;
                ah[mt] = *(const bf16x8*)&Ah[r * AST + ko];
                al[mt] = *(const bf16x8*)&Al[r * AST + ko];
            }
#pragma unroll
            for (int nt = 0; nt < 4; nt++) {
                int e = nt * 16 + l16;
                bf16x8 bh = *(const bf16x8*)&Bh[e * AST + ko];
                bf16x8 bl = *(const bf16x8*)&Bl[e * AST + ko];
#pragma unroll
                for (int mt = 0; mt < 2; mt++) {
                    acc[mt][nt] = __builtin_amdgcn_mfma_f32_16x16x32_bf16(ah[mt], bh, acc[mt][nt], 0, 0, 0);
                    acc[mt][nt] = __builtin_amdgcn_mfma_f32_16x16x32_bf16(ah[mt], bl, acc[mt][nt], 0, 0, 0);
                    acc[mt][nt] = __builtin_amdgcn_mfma_f32_16x16x32_bf16(al[mt], bh, acc[mt][nt], 0, 0, 0);
                }
            }
        }
        __syncthreads();
    }
    // epilogue: write Wh + f1/f2 partial dots
    float a1v[4], a2v[4];
#pragma unroll
    for (int nt = 0; nt < 4; nt++) {
        int e = e0 + nt * 16 + l16;
        a1v[nt] = ga[h * 2 * Dz + e];
        a2v[nt] = ga[h * 2 * Dz + Dz + e];
    }
    int rbase = row0 + wave * 32;
#pragma unroll
    for (int mt = 0; mt < 2; mt++) {
#pragma unroll
        for (int nt = 0; nt < 4; nt++) {
            int col = h * Dz + e0 + nt * 16 + l16;
#pragma unroll
            for (int reg = 0; reg < 4; reg++) {
                int row = rbase + mt * 16 + quad * 4 + reg;
                Wh[(size_t)row * (Hz * Dz) + col] = acc[mt][nt][reg];
            }
        }
#pragma unroll
        for (int reg = 0; reg < 4; reg++) {
            float s1 = acc[mt][0][reg] * a1v[0] + acc[mt][1][reg] * a1v[1]
                     + acc[mt][2][reg] * a1v[2] + acc[mt][3][reg] * a1v[3];
            float s2 = acc[mt][0][reg] * a2v[0] + acc[mt][1][reg] * a2v[1]
                     + acc[mt][2][reg] * a2v[2] + acc[mt][3][reg] * a2v[3];
#pragma unroll
            for (int m = 1; m < 16; m <<= 1) {
                s1 += __shfl_xor(s1, m);
                s2 += __shfl_xor(s2, m);
            }
            if (l16 == 0) {
                int row = rbase + mt * 16 + quad * 4 + reg;
                atomicAdd(&f1[(size_t)row * Hz + h], s1);
                atomicAdd(&f2[(size_t)row * Hz + h], s2);
            }
        }
    }
}

// ---------------- sparse GAT attention + head-mean aggregation ----------------------------
__global__ __launch_bounds__(128) void k_attn(const float* __restrict__ Wh,
                                              const float* __restrict__ f1,
                                              const float* __restrict__ f2,
                                              const int* __restrict__ idx,
                                              const int* __restrict__ cnt,
                                              float* __restrict__ G) {
    int row = blockIdx.x;                 // b*N + n
    int b = row >> 10;
    int t = threadIdx.x;                  // 128
    __shared__ int sidx[CAP];
    __shared__ float sat[Hz][CAP];
    __shared__ float sf1[Hz];
    int deg = cnt[row];
    if (t < Hz) sf1[t] = f1[(size_t)row * Hz + t];
    __syncthreads();
    if (deg > 0) {
        if (t < deg) {
            int m = idx[(size_t)row * CAP + t];
            sidx[t] = m;
            const float* f2m = f2 + ((size_t)(b << 10) + m) * Hz;
#pragma unroll
            for (int h = 0; h < Hz; h++) {
                float e = sf1[h] + f2m[h];
                e = e >= 0.f ? e : 0.2f * e;
                sat[h][t] = e;
            }
        }
        __syncthreads();
        if (t < Hz) {                     // per-head softmax over the deg entries
            float mx = -1e30f;
            for (int j = 0; j < deg; j++) mx = fmaxf(mx, sat[t][j]);
            float s = 0.f;
            for (int j = 0; j < deg; j++) {
                float v = expf(sat[t][j] - mx);
                sat[t][j] = v;
                s += v;
            }
            float inv = 1.f / s;
            for (int j = 0; j < deg; j++) sat[t][j] *= inv;
        }
        __syncthreads();
        float acc = 0.f;
        for (int j = 0; j < deg; j++) {
            int m = sidx[j];
            const float* wm = Wh + ((size_t)(b << 10) + m) * (Hz * Dz);
            acc += sat[0][j] * wm[t] + sat[1][j] * wm[Dz + t]
                 + sat[2][j] * wm[2 * Dz + t] + sat[3][j] * wm[3 * Dz + t];
        }
        G[(size_t)row * Dz + t] = acc * (1.f / Hz);
    } else {
        // all-masked row: softmax of constant -9e15 = uniform 1/N over ALL m (JAX semantics)
        float acc = 0.f;
        const float* wb = Wh + ((size_t)(b << 10)) * (Hz * Dz);
        for (int m = 0; m < Nz; m++) {
            const float* wm = wb + (size_t)m * Hz * Dz;
            acc += wm[t] + wm[Dz + t] + wm[2 * Dz + t] + wm[3 * Dz + t];
        }
        G[(size_t)row * Dz + t] = acc * (1.f / (Hz * Nz));
    }
}

// ---------------- hop pieces --------------------------------------------------------------
__global__ void k_uinit(const float* __restrict__ hidden, float* __restrict__ u) {
    u[blockIdx.x * Dz + threadIdx.x] = hidden[blockIdx.x * Dz + threadIdx.x];
}

__global__ void k_logits(const float* __restrict__ G, const float* __restrict__ u,
                         float* __restrict__ logits) {
    int row = blockIdx.x * 4 + (threadIdx.x >> 6);
    int lane = threadIdx.x & 63;
    int b = row >> 10;
    const float* g = G + (size_t)row * Dz;
    const float* ub = u + b * Dz;
    float s = g[lane] * ub[lane] + g[lane + 64] * ub[lane + 64];
#pragma unroll
    for (int off = 32; off; off >>= 1) s += __shfl_down(s, off);
    if (lane == 0) logits[row] = s;
}

__global__ void k_softmax(const float* __restrict__ logits, float* __restrict__ p) {
    int b = blockIdx.x;
    int t = threadIdx.x;                  // 256
    __shared__ float sh[16];
    const float* l = logits + (size_t)b * Nz;
    float mx = -1e30f;
    for (int i = t; i < Nz; i += 256) mx = fmaxf(mx, l[i]);
#pragma unroll
    for (int off = 32; off; off >>= 1) mx = fmaxf(mx, __shfl_down(mx, off));
    if ((t & 63) == 0) sh[t >> 6] = mx;
    __syncthreads();
    if (t == 0) {
        float m = sh[0];
        for (int i = 1; i < 4; i++) m = fmaxf(m, sh[i]);
        sh[0] = m;
    }
    __syncthreads();
    mx = sh[0];
    float s = 0.f;
    for (int i = t; i < Nz; i += 256) s += expf(l[i] - mx);
#pragma unroll
    for (int off = 32; off; off >>= 1) s += __shfl_down(s, off);
    if ((t & 63) == 0) sh[8 + (t >> 6)] = s;
    __syncthreads();
    if (t == 0) {
        float ss = 0.f;
        for (int i = 0; i < 4; i++) ss += sh[8 + i];
        sh[12] = ss;
    }
    __syncthreads();
    float inv = 1.f / sh[12];
    for (int i = t; i < Nz; i += 256) p[(size_t)b * Nz + i] = expf(l[i] - mx) * inv;
}

// u[b,d] += sum_n G[b,n,d] * p[b,n]; grid = B*8 chunks of 128 n
__global__ void k_uupd(const float* __restrict__ G, const float* __restrict__ p,
                       float* __restrict__ u) {
    int b = blockIdx.x >> 3;
    int c = blockIdx.x & 7;
    int d = threadIdx.x;                  // 128
    int n0 = c * 128;
    const float* g = G + ((size_t)b * Nz + n0) * Dz + d;
    const float* pb = p + (size_t)b * Nz + n0;
    float acc = 0.f;
#pragma unroll 4
    for (int j = 0; j < 128; j++) acc += g[(size_t)j * Dz] * pb[j];
    atomicAdd(&u[b * Dz + d], acc);
}

__global__ void k_final(const float* __restrict__ logits, const float* __restrict__ u,
                        float* __restrict__ out) {
    int i = blockIdx.x * 256 + threadIdx.x;
    if (i < Bz * Nz) {
        float l = logits[i];
        out[i] = 1.f / (1.f + expf(-l));
        out[Bz * Nz + Bz * Dz + i] = l;
    }
    if (i < Bz * Dz) out[Bz * Nz + i] = u[i];
}

// ---------------- host ---------------------------------------------------------------------
extern "C" void kernel_launch(void* const* d_in, const int* in_sizes, int n_in,
                              void* d_out, int out_size, void* d_ws, size_t ws_size,
                              hipStream_t stream) {
    const int*   story    = (const int*)d_in[0];
    const int*   kb_len   = (const int*)d_in[1];
    const int*   conv_len = (const int*)d_in[2];
    const float* hidden   = (const float*)d_in[3];
    const float* dh       = (const float*)d_in[4];
    const float* adj      = (const float*)d_in[5];
    const float* emb      = (const float*)d_in[6];
    const float* gat_W    = (const float*)d_in[7];
    const float* gat_a    = (const float*)d_in[8];
    float* out = (float*)d_out;

    char* w = (char*)d_ws;
    auto alloc = [&](size_t bytes) {
        char* pp = w;
        w += (bytes + 255) & ~(size_t)255;
        return pp;
    };
    const size_t BN = (size_t)Bz * Nz;
    int*            idx    = (int*)           alloc(BN * CAP * 4);
    int*            cnt    = (int*)           alloc(BN * 4);
    unsigned short* xhi    = (unsigned short*)alloc(BN * Dz * 2);
    unsigned short* xlo    = (unsigned short*)alloc(BN * Dz * 2);
    unsigned short* wthi   = (unsigned short*)alloc(4 * Hz * Dz * Dz * 2);
    unsigned short* wtlo   = (unsigned short*)alloc(4 * Hz * Dz * Dz * 2);
    float*          Wh     = (float*)         alloc(BN * Hz * Dz * 4);
    float*          f1     = (float*)         alloc(BN * Hz * 4);
    float*          f2     = (float*)         alloc(BN * Hz * 4);
    float*          GA     = (float*)         alloc(BN * Dz * 4);
    float*          GB     = (float*)         alloc(BN * Dz * 4);
    float*          logits = (float*)         alloc(BN * 4);
    float*          p      = (float*)         alloc(BN * 4);
    float*          u      = (float*)         alloc((size_t)Bz * Dz * 4);

    k_csr<<<BN, 256, 0, stream>>>(adj, kb_len, conv_len, idx, cnt);
    k_wsplit<<<4 * Hz * Dz * Dz / 256, 256, 0, stream>>>(gat_W, wthi, wtlo);
    k_uinit<<<Bz, Dz, 0, stream>>>(hidden, u);

    auto computeG = [&](int k, float* G) {
        k_embed<<<BN, Dz, 0, stream>>>(story, emb + (size_t)k * VOCABz * Dz, dh, kb_len,
                                       conv_len, xhi, xlo, f1, f2);
        k_whf<<<dim3(8, 128), 256, 0, stream>>>(xhi, xlo, wthi + (size_t)k * Hz * Dz * Dz,
                                                wtlo + (size_t)k * Hz * Dz * Dz,
                                                gat_a + (size_t)k * Hz * 2 * Dz, Wh, f1, f2);
        k_attn<<<BN, 128, 0, stream>>>(Wh, f1, f2, idx, cnt, G);
    };

    computeG(0, GA);
    computeG(1, GB);
    // hop 0: A=G0 (GA), Cm=G1 (GB)
    k_logits<<<BN / 4, 256, 0, stream>>>(GA, u, logits);
    k_softmax<<<Bz, 256, 0, stream>>>(logits, p);
    k_uupd<<<Bz * 8, Dz, 0, stream>>>(GB, p, u);
    computeG(2, GA);
    // hop 1: A=G1 (GB), Cm=G2 (GA)
    k_logits<<<BN / 4, 256, 0, stream>>>(GB, u, logits);
    k_softmax<<<Bz, 256, 0, stream>>>(logits, p);
    k_uupd<<<Bz * 8, Dz, 0, stream>>>(GA, p, u);
    computeG(3, GB);
    // hop 2: A=G2 (GA), Cm=G3 (GB)
    k_logits<<<BN / 4, 256, 0, stream>>>(GA, u, logits);
    k_softmax<<<Bz, 256, 0, stream>>>(logits, p);
    k_uupd<<<Bz * 8, Dz, 0, stream>>>(GB, p, u);

    k_final<<<(Bz * Nz + 255) / 256, 256, 0, stream>>>(logits, u, out);
}

// Round 3
// 491.107 us; speedup vs baseline: 1.4273x; 1.1754x over previous
//
#include <hip/hip_runtime.h>
#include <hip/hip_bf16.h>
#include <math.h>

#define Bz 16
#define Nz 1024
#define Mz 4
#define Dz 128
#define Hz 4
#define VOCABz 32000
#define CAP 128
#define BNc (Bz * Nz)

typedef __attribute__((ext_vector_type(8))) short bf16x8;
typedef __attribute__((ext_vector_type(4))) float f32x4;

__device__ inline unsigned short rne_bf16(float x) {
    unsigned u = __float_as_uint(x);
    unsigned r = (u + 0x7FFFu + ((u >> 16) & 1u)) >> 16;
    return (unsigned short)r;
}
__device__ inline float bf16_to_f(unsigned short h) {
    return __uint_as_float(((unsigned)h) << 16);
}

// ---------------- CSR build: mask[b,n,m] = adj>0 || (m==n && n>=kb_len+conv_len) ----------
__global__ void k_csr(const float* __restrict__ adj, const int* __restrict__ kb_len,
                      const int* __restrict__ conv_len, int* __restrict__ idx,
                      int* __restrict__ cnt) {
    int row = blockIdx.x;                 // b*N + n
    int b = row >> 10, n = row & 1023;
    __shared__ int scnt;
    if (threadIdx.x == 0) scnt = 0;
    __syncthreads();
    int ctx = kb_len[b] + conv_len[b];
    const float* arow = adj + (size_t)row * Nz;
    for (int m = threadIdx.x; m < Nz; m += blockDim.x) {
        bool on = (arow[m] > 0.f) || (m == n && n >= ctx);
        if (on) {
            int p = atomicAdd(&scnt, 1);
            if (p < CAP) idx[(size_t)row * CAP + p] = m;
        }
    }
    __syncthreads();
    if (threadIdx.x == 0) cnt[row] = scnt < CAP ? scnt : CAP;
}

// ---------------- W pre-split+transpose: WT[k][h][e][d] hi/lo bf16 ------------------------
__global__ void k_wsplit(const float* __restrict__ gat_W, unsigned short* __restrict__ wthi,
                         unsigned short* __restrict__ wtlo) {
    int i = blockIdx.x * 256 + threadIdx.x;       // 4*4*128*128 = 262144
    int d = i & 127;
    int e = (i >> 7) & 127;
    int kh = i >> 14;
    float v = gat_W[((size_t)kh * 128 + d) * 128 + e];
    unsigned short h = rne_bf16(v);
    float lo = v - bf16_to_f(h);
    wthi[i] = h;
    wtlo[i] = rne_bf16(lo);
}

// ---------------- embed: x = sum emb rows (+ dh scatter), split to bf16 hi/lo -------------
__global__ void k_embed(const int* __restrict__ story, const float* __restrict__ emb_k,
                        const float* __restrict__ dh, const int* __restrict__ kb_len,
                        const int* __restrict__ conv_len, unsigned short* __restrict__ xhi,
                        unsigned short* __restrict__ xlo) {
    int row = blockIdx.x;                 // b*N + n
    int b = row >> 10, n = row & 1023;
    int d = threadIdx.x;                  // 128
    const int* st = story + (size_t)row * Mz;
    int s0 = st[0], s1 = st[1], s2 = st[2], s3 = st[3];
    float acc = emb_k[(size_t)s0 * Dz + d] + emb_k[(size_t)s1 * Dz + d]
              + emb_k[(size_t)s2 * Dz + d] + emb_k[(size_t)s3 * Dz + d];
    int rel = n - (kb_len[b] - 1);
    if (rel >= 0 && rel < conv_len[b]) acc += dh[((size_t)b * Nz + rel) * Dz + d];
    unsigned short hb = rne_bf16(acc);
    float lo = acc - bf16_to_f(hb);
    xhi[(size_t)row * Dz + d] = hb;
    xlo[(size_t)row * Dz + d] = rne_bf16(lo);
}

// ---------------- Wh GEMM via bf16x3 MFMA; writes WhT bf16 [row][e][h] + f1/f2 halves -----
// grid (8 = h*2+half, 128 rowtiles), 256 threads (4 waves). K in 2 phases of 64.
#define AST 72
__global__ __launch_bounds__(256) void k_whf(const unsigned short* __restrict__ xhi,
                                             const unsigned short* __restrict__ xlo,
                                             const unsigned short* __restrict__ wthi,
                                             const unsigned short* __restrict__ wtlo,
                                             const float* __restrict__ ga,
                                             unsigned short* __restrict__ WhT,
                                             float* __restrict__ f1p,
                                             float* __restrict__ f2p) {
    int h = blockIdx.x >> 1;
    int half = blockIdx.x & 1;
    int e0 = half * 64;
    int row0 = blockIdx.y * 128;
    int t = threadIdx.x;
    int wave = t >> 6, lane = t & 63;
    int quad = lane >> 4, l16 = lane & 15;

    __shared__ unsigned short Ah[128 * AST], Al[128 * AST];   // X tile hi/lo [r][k]
    __shared__ unsigned short Bh[64 * AST], Bl[64 * AST];     // WT tile hi/lo [e][d]

    f32x4 acc[2][4];
#pragma unroll
    for (int mt = 0; mt < 2; mt++)
#pragma unroll
        for (int nt = 0; nt < 4; nt++) acc[mt][nt] = (f32x4)0.f;

    for (int ph = 0; ph < 2; ph++) {
        int kb = ph * 64;
        for (int i = t; i < 1024; i += 256) {
            int r = i >> 3, c = (i & 7) * 8;
            *(uint4*)&Ah[r * AST + c] = *(const uint4*)&xhi[(size_t)(row0 + r) * Dz + kb + c];
            *(uint4*)&Al[r * AST + c] = *(const uint4*)&xlo[(size_t)(row0 + r) * Dz + kb + c];
        }
        for (int i = t; i < 512; i += 256) {
            int e = i >> 3, c = (i & 7) * 8;
            size_t src = ((size_t)h * 128 + e0 + e) * 128 + kb + c;
            *(uint4*)&Bh[e * AST + c] = *(const uint4*)&wthi[src];
            *(uint4*)&Bl[e * AST + c] = *(const uint4*)&wtlo[src];
        }
        __syncthreads();
#pragma unroll
        for (int ks = 0; ks < 2; ks++) {
            int ko = ks * 32 + quad * 8;
            bf16x8 ah[2], al[2];
#pragma unroll
            for (int mt = 0; mt < 2; mt++) {
                int r = wave * 32 + mt * 16 + l16;
                ah[mt] = *(const bf16x8*)&Ah[r * AST + ko];
                al[mt] = *(const bf16x8*)&Al[r * AST + ko];
            }
#pragma unroll
            for (int nt = 0; nt < 4; nt++) {
                int e = nt * 16 + l16;
                bf16x8 bh = *(const bf16x8*)&Bh[e * AST + ko];
                bf16x8 bl = *(const bf16x8*)&Bl[e * AST + ko];
#pragma unroll
                for (int mt = 0; mt < 2; mt++) {
                    acc[mt][nt] = __builtin_amdgcn_mfma_f32_16x16x32_bf16(ah[mt], bh, acc[mt][nt], 0, 0, 0);
                    acc[mt][nt] = __builtin_amdgcn_mfma_f32_16x16x32_bf16(ah[mt], bl, acc[mt][nt], 0, 0, 0);
                    acc[mt][nt] = __builtin_amdgcn_mfma_f32_16x16x32_bf16(al[mt], bh, acc[mt][nt], 0, 0, 0);
                }
            }
        }
        __syncthreads();
    }
    // epilogue: WhT bf16 [row*512 + e*4 + h] + f1/f2 half-partials (no atomics)
    float a1v[4], a2v[4];
#pragma unroll
    for (int nt = 0; nt < 4; nt++) {
        int e = e0 + nt * 16 + l16;
        a1v[nt] = ga[h * 2 * Dz + e];
        a2v[nt] = ga[h * 2 * Dz + Dz + e];
    }
    int rbase = row0 + wave * 32;
#pragma unroll
    for (int mt = 0; mt < 2; mt++) {
#pragma unroll
        for (int nt = 0; nt < 4; nt++) {
            int e = e0 + nt * 16 + l16;
#pragma unroll
            for (int reg = 0; reg < 4; reg++) {
                int row = rbase + mt * 16 + quad * 4 + reg;
                WhT[(size_t)row * 512 + e * 4 + h] = rne_bf16(acc[mt][nt][reg]);
            }
        }
#pragma unroll
        for (int reg = 0; reg < 4; reg++) {
            float s1 = acc[mt][0][reg] * a1v[0] + acc[mt][1][reg] * a1v[1]
                     + acc[mt][2][reg] * a1v[2] + acc[mt][3][reg] * a1v[3];
            float s2 = acc[mt][0][reg] * a2v[0] + acc[mt][1][reg] * a2v[1]
                     + acc[mt][2][reg] * a2v[2] + acc[mt][3][reg] * a2v[3];
#pragma unroll
            for (int m = 1; m < 16; m <<= 1) {
                s1 += __shfl_xor(s1, m);
                s2 += __shfl_xor(s2, m);
            }
            if (l16 == 0) {
                int row = rbase + mt * 16 + quad * 4 + reg;
                f1p[((size_t)half * BNc + row) * Hz + h] = s1;
                f2p[((size_t)half * BNc + row) * Hz + h] = s2;
            }
        }
    }
}

// ---------------- sparse GAT attention + head-mean aggregation ----------------------------
// XCD swizzle: blk&7 -> 2 batches per XCD so WhT b-slices stay L2-resident.
__global__ __launch_bounds__(128) void k_attn(const unsigned short* __restrict__ WhT,
                                              const float* __restrict__ f1p,
                                              const float* __restrict__ f2p,
                                              const int* __restrict__ idx,
                                              const int* __restrict__ cnt,
                                              float* __restrict__ G) {
    int blk = blockIdx.x;
    int b = ((blk & 7) << 1) | ((blk >> 3) >> 10);
    int n = (blk >> 3) & 1023;
    int row = (b << 10) | n;
    int t = threadIdx.x;                  // 128
    __shared__ int sidx[CAP];
    __shared__ float sat[Hz][CAP];
    __shared__ float red[8];
    int deg = cnt[row];
    if (deg > 0) {
        if (t < deg) {
            int m = idx[(size_t)row * CAP + t];
            sidx[t] = m;
            int mrow = (b << 10) | m;
            float4 f2a = *(const float4*)&f2p[(size_t)mrow * Hz];
            float4 f2b = *(const float4*)&f2p[((size_t)BNc + mrow) * Hz];
            float4 f1a = *(const float4*)&f1p[(size_t)row * Hz];
            float4 f1b = *(const float4*)&f1p[((size_t)BNc + row) * Hz];
            float e0v = (f1a.x + f1b.x) + (f2a.x + f2b.x);
            float e1v = (f1a.y + f1b.y) + (f2a.y + f2b.y);
            float e2v = (f1a.z + f1b.z) + (f2a.z + f2b.z);
            float e3v = (f1a.w + f1b.w) + (f2a.w + f2b.w);
            sat[0][t] = e0v >= 0.f ? e0v : 0.2f * e0v;
            sat[1][t] = e1v >= 0.f ? e1v : 0.2f * e1v;
            sat[2][t] = e2v >= 0.f ? e2v : 0.2f * e2v;
            sat[3][t] = e3v >= 0.f ? e3v : 0.2f * e3v;
        }
        __syncthreads();
        int h = t >> 5, j0 = t & 31;      // 32 threads per head
        float mx = -1e30f;
        for (int j = j0; j < deg; j += 32) mx = fmaxf(mx, sat[h][j]);
#pragma unroll
        for (int mm = 1; mm < 32; mm <<= 1) mx = fmaxf(mx, __shfl_xor(mx, mm));
        if (j0 == 0) red[h] = mx;
        __syncthreads();
        mx = red[h];
        float s = 0.f;
        for (int j = j0; j < deg; j += 32) {
            float v = expf(sat[h][j] - mx);
            sat[h][j] = v;
            s += v;
        }
#pragma unroll
        for (int mm = 1; mm < 32; mm <<= 1) s += __shfl_xor(s, mm);
        if (j0 == 0) red[4 + h] = 0.25f / s;      // fold 1/Hz into the weights
        __syncthreads();
        float invh = red[4 + h];
        for (int j = j0; j < deg; j += 32) sat[h][j] *= invh;
        __syncthreads();
        float acc = 0.f;
        const unsigned short* wb = WhT + ((size_t)(b << 10)) * 512 + t * 4;
        for (int j = 0; j < deg; j++) {
            int m = sidx[j];
            uint2 raw = *(const uint2*)(wb + (size_t)m * 512);
            float w0 = __uint_as_float(raw.x << 16);
            float w1 = __uint_as_float(raw.x & 0xFFFF0000u);
            float w2 = __uint_as_float(raw.y << 16);
            float w3 = __uint_as_float(raw.y & 0xFFFF0000u);
            acc += sat[0][j] * w0 + sat[1][j] * w1 + sat[2][j] * w2 + sat[3][j] * w3;
        }
        G[(size_t)row * Dz + t] = acc;
    } else {
        // all-masked row: softmax of constant -9e15 = uniform 1/N over ALL m (JAX semantics)
        float acc = 0.f;
        const unsigned short* wb = WhT + ((size_t)(b << 10)) * 512 + t * 4;
        for (int m = 0; m < Nz; m++) {
            uint2 raw = *(const uint2*)(wb + (size_t)m * 512);
            acc += __uint_as_float(raw.x << 16) + __uint_as_float(raw.x & 0xFFFF0000u)
                 + __uint_as_float(raw.y << 16) + __uint_as_float(raw.y & 0xFFFF0000u);
        }
        G[(size_t)row * Dz + t] = acc * (1.f / (Hz * Nz));
    }
}

// ---------------- hop pieces --------------------------------------------------------------
__global__ void k_uinit(const float* __restrict__ hidden, float* __restrict__ u) {
    u[blockIdx.x * Dz + threadIdx.x] = hidden[blockIdx.x * Dz + threadIdx.x];
}

__global__ void k_logits(const float* __restrict__ G, const float* __restrict__ u,
                         float* __restrict__ logits) {
    int row = blockIdx.x * 4 + (threadIdx.x >> 6);
    int lane = threadIdx.x & 63;
    int b = row >> 10;
    const float* g = G + (size_t)row * Dz;
    const float* ub = u + b * Dz;
    float s = g[lane] * ub[lane] + g[lane + 64] * ub[lane + 64];
#pragma unroll
    for (int off = 32; off; off >>= 1) s += __shfl_down(s, off);
    if (lane == 0) logits[row] = s;
}

__global__ void k_softmax(const float* __restrict__ logits, float* __restrict__ p) {
    int b = blockIdx.x;
    int t = threadIdx.x;                  // 256
    __shared__ float sh[16];
    const float* l = logits + (size_t)b * Nz;
    float mx = -1e30f;
    for (int i = t; i < Nz; i += 256) mx = fmaxf(mx, l[i]);
#pragma unroll
    for (int off = 32; off; off >>= 1) mx = fmaxf(mx, __shfl_down(mx, off));
    if ((t & 63) == 0) sh[t >> 6] = mx;
    __syncthreads();
    if (t == 0) {
        float m = sh[0];
        for (int i = 1; i < 4; i++) m = fmaxf(m, sh[i]);
        sh[0] = m;
    }
    __syncthreads();
    mx = sh[0];
    float s = 0.f;
    for (int i = t; i < Nz; i += 256) s += expf(l[i] - mx);
#pragma unroll
    for (int off = 32; off; off >>= 1) s += __shfl_down(s, off);
    if ((t & 63) == 0) sh[8 + (t >> 6)] = s;
    __syncthreads();
    if (t == 0) {
        float ss = 0.f;
        for (int i = 0; i < 4; i++) ss += sh[8 + i];
        sh[12] = ss;
    }
    __syncthreads();
    float inv = 1.f / sh[12];
    for (int i = t; i < Nz; i += 256) p[(size_t)b * Nz + i] = expf(l[i] - mx) * inv;
}

// u[b,d] += sum_n G[b,n,d] * p[b,n]; grid = B*8 chunks of 128 n
__global__ void k_uupd(const float* __restrict__ G, const float* __restrict__ p,
                       float* __restrict__ u) {
    int b = blockIdx.x >> 3;
    int c = blockIdx.x & 7;
    int d = threadIdx.x;                  // 128
    int n0 = c * 128;
    const float* g = G + ((size_t)b * Nz + n0) * Dz + d;
    const float* pb = p + (size_t)b * Nz + n0;
    float acc = 0.f;
#pragma unroll 4
    for (int j = 0; j < 128; j++) acc += g[(size_t)j * Dz] * pb[j];
    atomicAdd(&u[b * Dz + d], acc);
}

__global__ void k_final(const float* __restrict__ logits, const float* __restrict__ u,
                        float* __restrict__ out) {
    int i = blockIdx.x * 256 + threadIdx.x;
    if (i < Bz * Nz) {
        float l = logits[i];
        out[i] = 1.f / (1.f + expf(-l));
        out[Bz * Nz + Bz * Dz + i] = l;
    }
    if (i < Bz * Dz) out[Bz * Nz + i] = u[i];
}

// ---------------- host ---------------------------------------------------------------------
extern "C" void kernel_launch(void* const* d_in, const int* in_sizes, int n_in,
                              void* d_out, int out_size, void* d_ws, size_t ws_size,
                              hipStream_t stream) {
    const int*   story    = (const int*)d_in[0];
    const int*   kb_len   = (const int*)d_in[1];
    const int*   conv_len = (const int*)d_in[2];
    const float* hidden   = (const float*)d_in[3];
    const float* dh       = (const float*)d_in[4];
    const float* adj      = (const float*)d_in[5];
    const float* emb      = (const float*)d_in[6];
    const float* gat_W    = (const float*)d_in[7];
    const float* gat_a    = (const float*)d_in[8];
    float* out = (float*)d_out;

    char* w = (char*)d_ws;
    auto alloc = [&](size_t bytes) {
        char* pp = w;
        w += (bytes + 255) & ~(size_t)255;
        return pp;
    };
    const size_t BN = (size_t)Bz * Nz;
    int*            idx    = (int*)           alloc(BN * CAP * 4);
    int*            cnt    = (int*)           alloc(BN * 4);
    unsigned short* xhi    = (unsigned short*)alloc(BN * Dz * 2);
    unsigned short* xlo    = (unsigned short*)alloc(BN * Dz * 2);
    unsigned short* wthi   = (unsigned short*)alloc(4 * Hz * Dz * Dz * 2);
    unsigned short* wtlo   = (unsigned short*)alloc(4 * Hz * Dz * Dz * 2);
    unsigned short* WhT    = (unsigned short*)alloc(BN * Hz * Dz * 2);
    float*          f1p    = (float*)         alloc(2 * BN * Hz * 4);
    float*          f2p    = (float*)         alloc(2 * BN * Hz * 4);
    float*          GA     = (float*)         alloc(BN * Dz * 4);
    float*          GB     = (float*)         alloc(BN * Dz * 4);
    float*          logits = (float*)         alloc(BN * 4);
    float*          p      = (float*)         alloc(BN * 4);
    float*          u      = (float*)         alloc((size_t)Bz * Dz * 4);

    k_csr<<<BN, 256, 0, stream>>>(adj, kb_len, conv_len, idx, cnt);
    k_wsplit<<<4 * Hz * Dz * Dz / 256, 256, 0, stream>>>(gat_W, wthi, wtlo);
    k_uinit<<<Bz, Dz, 0, stream>>>(hidden, u);

    auto computeG = [&](int k, float* G) {
        k_embed<<<BN, Dz, 0, stream>>>(story, emb + (size_t)k * VOCABz * Dz, dh, kb_len,
                                       conv_len, xhi, xlo);
        k_whf<<<dim3(8, 128), 256, 0, stream>>>(xhi, xlo, wthi + (size_t)k * Hz * Dz * Dz,
                                                wtlo + (size_t)k * Hz * Dz * Dz,
                                                gat_a + (size_t)k * Hz * 2 * Dz, WhT, f1p, f2p);
        k_attn<<<BN, 128, 0, stream>>>(WhT, f1p, f2p, idx, cnt, G);
    };

    computeG(0, GA);
    computeG(1, GB);
    // hop 0: A=G0 (GA), Cm=G1 (GB)
    k_logits<<<BN / 4, 256, 0, stream>>>(GA, u, logits);
    k_softmax<<<Bz, 256, 0, stream>>>(logits, p);
    k_uupd<<<Bz * 8, Dz, 0, stream>>>(GB, p, u);
    computeG(2, GA);
    // hop 1: A=G1 (GB), Cm=G2 (GA)
    k_logits<<<BN / 4, 256, 0, stream>>>(GB, u, logits);
    k_softmax<<<Bz, 256, 0, stream>>>(logits, p);
    k_uupd<<<Bz * 8, Dz, 0, stream>>>(GA, p, u);
    computeG(3, GB);
    // hop 2: A=G2 (GA), Cm=G3 (GB)
    k_logits<<<BN / 4, 256, 0, stream>>>(GA, u, logits);
    k_softmax<<<Bz, 256, 0, stream>>>(logits, p);
    k_uupd<<<Bz * 8, Dz, 0, stream>>>(GB, p, u);

    k_final<<<(Bz * Nz + 255) / 256, 256, 0, stream>>>(logits, u, out);
}

// Round 4
// 480.058 us; speedup vs baseline: 1.4602x; 1.0230x over previous
//
#include <hip/hip_runtime.h>
#include <hip/hip_bf16.h>
#include <math.h>

#define Bz 16
#define Nz 1024
#define Mz 4
#define Dz 128
#define Hz 4
#define VOCABz 32000
#define CAP 128
#define BNc (Bz * Nz)

typedef __attribute__((ext_vector_type(8))) short bf16x8;
typedef __attribute__((ext_vector_type(4))) float f32x4;

__device__ inline unsigned short rne_bf16(float x) {
    unsigned u = __float_as_uint(x);
    unsigned r = (u + 0x7FFFu + ((u >> 16) & 1u)) >> 16;
    return (unsigned short)r;
}
__device__ inline float bf16_to_f(unsigned short h) {
    return __uint_as_float(((unsigned)h) << 16);
}

// ---------------- prep: CSR build (blocks 0..16383) + W split (16384..17407) + uinit ------
__global__ __launch_bounds__(256) void k_prep(const float* __restrict__ adj,
                                              const int* __restrict__ kb_len,
                                              const int* __restrict__ conv_len,
                                              const float* __restrict__ gat_W,
                                              const float* __restrict__ hidden,
                                              int* __restrict__ idx, int* __restrict__ cnt,
                                              unsigned short* __restrict__ wthi,
                                              unsigned short* __restrict__ wtlo,
                                              float* __restrict__ u) {
    int blk = blockIdx.x;
    int t = threadIdx.x;
    if (blk < BNc) {                      // CSR row
        int row = blk;
        int b = row >> 10, n = row & 1023;
        __shared__ int scnt;
        if (t == 0) scnt = 0;
        __syncthreads();
        int ctx = kb_len[b] + conv_len[b];
        const float4 av = *((const float4*)(adj + (size_t)row * Nz) + t);
        int m0 = t * 4;
#pragma unroll
        for (int k = 0; k < 4; k++) {
            float a = k == 0 ? av.x : k == 1 ? av.y : k == 2 ? av.z : av.w;
            int m = m0 + k;
            bool on = (a > 0.f) || (m == n && n >= ctx);
            if (on) {
                int p = atomicAdd(&scnt, 1);
                if (p < CAP) idx[(size_t)row * CAP + p] = m;
            }
        }
        __syncthreads();
        if (t == 0) cnt[row] = scnt < CAP ? scnt : CAP;
    } else if (blk < BNc + 1024) {        // W split+transpose
        int i = (blk - BNc) * 256 + t;    // 262144 total
        int d = i & 127;
        int e = (i >> 7) & 127;
        int kh = i >> 14;
        float v = gat_W[((size_t)kh * 128 + d) * 128 + e];
        unsigned short h = rne_bf16(v);
        wthi[i] = h;
        wtlo[i] = rne_bf16(v - bf16_to_f(h));
    } else {                              // u init
        int i = (blk - BNc - 1024) * 256 + t;
        if (i < Bz * Dz) u[i] = hidden[i];
    }
}

// ---------------- embed all 4 hops: x = sum emb rows (+ dh), split to bf16 hi/lo ----------
__global__ __launch_bounds__(128) void k_embed4(const int* __restrict__ story,
                                                const float* __restrict__ emb,
                                                const float* __restrict__ dh,
                                                const int* __restrict__ kb_len,
                                                const int* __restrict__ conv_len,
                                                unsigned short* __restrict__ xhi,
                                                unsigned short* __restrict__ xlo) {
    int row = blockIdx.x;                 // b*N + n
    int b = row >> 10, n = row & 1023;
    int d = threadIdx.x;                  // 128
    const int* st = story + (size_t)row * Mz;
    int s0 = st[0], s1 = st[1], s2 = st[2], s3 = st[3];
    int rel = n - (kb_len[b] - 1);
    float dhv = (rel >= 0 && rel < conv_len[b]) ? dh[((size_t)(b << 10) + rel) * Dz + d] : 0.f;
#pragma unroll
    for (int hop = 0; hop < 4; hop++) {
        const float* ek = emb + (size_t)hop * VOCABz * Dz;
        float acc = ek[(size_t)s0 * Dz + d] + ek[(size_t)s1 * Dz + d]
                  + ek[(size_t)s2 * Dz + d] + ek[(size_t)s3 * Dz + d] + dhv;
        unsigned short hb = rne_bf16(acc);
        size_t o = (size_t)hop * BNc * Dz + (size_t)row * Dz + d;
        xhi[o] = hb;
        xlo[o] = rne_bf16(acc - bf16_to_f(hb));
    }
}

// ---------------- Wh GEMM (bf16x3 MFMA) for all hops; WhT bf16 [hop][row][e][h] -----------
// grid (8 = h*2+half, 128 rowtiles, 4 hops), 256 threads (4 waves). K in 2 phases of 64.
#define AST 72
__global__ __launch_bounds__(256) void k_whf4(const unsigned short* __restrict__ xhi_a,
                                              const unsigned short* __restrict__ xlo_a,
                                              const unsigned short* __restrict__ wthi_a,
                                              const unsigned short* __restrict__ wtlo_a,
                                              const float* __restrict__ gat_a,
                                              unsigned short* __restrict__ WhT_a,
                                              float* __restrict__ f1p,
                                              float* __restrict__ f2p) {
    int hop = blockIdx.z;
    int h = blockIdx.x >> 1;
    int half = blockIdx.x & 1;
    int e0 = half * 64;
    int row0 = blockIdx.y * 128;
    int t = threadIdx.x;
    int wave = t >> 6, lane = t & 63;
    int quad = lane >> 4, l16 = lane & 15;

    const unsigned short* xhi = xhi_a + (size_t)hop * BNc * Dz;
    const unsigned short* xlo = xlo_a + (size_t)hop * BNc * Dz;
    const unsigned short* wthi = wthi_a + (size_t)hop * Hz * Dz * Dz;
    const unsigned short* wtlo = wtlo_a + (size_t)hop * Hz * Dz * Dz;
    const float* ga = gat_a + (size_t)hop * Hz * 2 * Dz;
    unsigned short* WhT = WhT_a + (size_t)hop * BNc * 512;

    __shared__ unsigned short Ah[128 * AST], Al[128 * AST];   // X tile hi/lo [r][k]
    __shared__ unsigned short Bh[64 * AST], Bl[64 * AST];     // WT tile hi/lo [e][d]

    f32x4 acc[2][4];
#pragma unroll
    for (int mt = 0; mt < 2; mt++)
#pragma unroll
        for (int nt = 0; nt < 4; nt++) acc[mt][nt] = (f32x4)0.f;

    for (int ph = 0; ph < 2; ph++) {
        int kb = ph * 64;
        for (int i = t; i < 1024; i += 256) {
            int r = i >> 3, c = (i & 7) * 8;
            *(uint4*)&Ah[r * AST + c] = *(const uint4*)&xhi[(size_t)(row0 + r) * Dz + kb + c];
            *(uint4*)&Al[r * AST + c] = *(const uint4*)&xlo[(size_t)(row0 + r) * Dz + kb + c];
        }
        for (int i = t; i < 512; i += 256) {
            int e = i >> 3, c = (i & 7) * 8;
            size_t src = ((size_t)h * 128 + e0 + e) * 128 + kb + c;
            *(uint4*)&Bh[e * AST + c] = *(const uint4*)&wthi[src];
            *(uint4*)&Bl[e * AST + c] = *(const uint4*)&wtlo[src];
        }
        __syncthreads();
#pragma unroll
        for (int ks = 0; ks < 2; ks++) {
            int ko = ks * 32 + quad * 8;
            bf16x8 ah[2], al[2];
#pragma unroll
            for (int mt = 0; mt < 2; mt++) {
                int r = wave * 32 + mt * 16 + l16;
                ah[mt] = *(const bf16x8*)&Ah[r * AST + ko];
                al[mt] = *(const bf16x8*)&Al[r * AST + ko];
            }
#pragma unroll
            for (int nt = 0; nt < 4; nt++) {
                int e = nt * 16 + l16;
                bf16x8 bh = *(const bf16x8*)&Bh[e * AST + ko];
                bf16x8 bl = *(const bf16x8*)&Bl[e * AST + ko];
#pragma unroll
                for (int mt = 0; mt < 2; mt++) {
                    acc[mt][nt] = __builtin_amdgcn_mfma_f32_16x16x32_bf16(ah[mt], bh, acc[mt][nt], 0, 0, 0);
                    acc[mt][nt] = __builtin_amdgcn_mfma_f32_16x16x32_bf16(ah[mt], bl, acc[mt][nt], 0, 0, 0);
                    acc[mt][nt] = __builtin_amdgcn_mfma_f32_16x16x32_bf16(al[mt], bh, acc[mt][nt], 0, 0, 0);
                }
            }
        }
        __syncthreads();
    }
    // epilogue: WhT bf16 [row*512 + e*4 + h] + f1/f2 half-partials (no atomics)
    float a1v[4], a2v[4];
#pragma unroll
    for (int nt = 0; nt < 4; nt++) {
        int e = e0 + nt * 16 + l16;
        a1v[nt] = ga[h * 2 * Dz + e];
        a2v[nt] = ga[h * 2 * Dz + Dz + e];
    }
    int rbase = row0 + wave * 32;
#pragma unroll
    for (int mt = 0; mt < 2; mt++) {
#pragma unroll
        for (int nt = 0; nt < 4; nt++) {
            int e = e0 + nt * 16 + l16;
#pragma unroll
            for (int reg = 0; reg < 4; reg++) {
                int row = rbase + mt * 16 + quad * 4 + reg;
                WhT[(size_t)row * 512 + e * 4 + h] = rne_bf16(acc[mt][nt][reg]);
            }
        }
#pragma unroll
        for (int reg = 0; reg < 4; reg++) {
            float s1 = acc[mt][0][reg] * a1v[0] + acc[mt][1][reg] * a1v[1]
                     + acc[mt][2][reg] * a1v[2] + acc[mt][3][reg] * a1v[3];
            float s2 = acc[mt][0][reg] * a2v[0] + acc[mt][1][reg] * a2v[1]
                     + acc[mt][2][reg] * a2v[2] + acc[mt][3][reg] * a2v[3];
#pragma unroll
            for (int m = 1; m < 16; m <<= 1) {
                s1 += __shfl_xor(s1, m);
                s2 += __shfl_xor(s2, m);
            }
            if (l16 == 0) {
                int row = rbase + mt * 16 + quad * 4 + reg;
                size_t o = ((size_t)(hop * 2 + half) * BNc + row) * Hz + h;
                f1p[o] = s1;
                f2p[o] = s2;
            }
        }
    }
}

// ---------------- sparse GAT attention for all hops ---------------------------------------
// XCD swizzle: blk&7 = XCD; 128 consecutive per-XCD blocks share one (hop,b) 2MB WhT slice.
__global__ __launch_bounds__(128) void k_attn4(const unsigned short* __restrict__ WhT_a,
                                               const float* __restrict__ f1p,
                                               const float* __restrict__ f2p,
                                               const int* __restrict__ idx,
                                               const int* __restrict__ cnt,
                                               float* __restrict__ G_a) {
    int blk = blockIdx.x;
    int xcd = blk & 7;
    int s = blk >> 3;                     // 0..8191
    int pair = s >> 7;                    // 0..63
    int hop = pair >> 4;
    int b = pair & 15;
    int n = ((s & 127) << 3) | xcd;
    int row = (b << 10) | n;
    int t = threadIdx.x;                  // 128
    __shared__ int sidx[CAP];
    __shared__ float sat[Hz][CAP];
    __shared__ float red[8];
    int deg = cnt[row];
    const unsigned short* WhTb = WhT_a + ((size_t)hop * BNc + ((size_t)b << 10)) * 512;
    if (deg > 0) {
        if (t < deg) {
            int m = idx[(size_t)row * CAP + t];
            sidx[t] = m;
            int mrow = (b << 10) | m;
            float4 f2a = *(const float4*)&f2p[((size_t)(hop * 2) * BNc + mrow) * Hz];
            float4 f2b = *(const float4*)&f2p[((size_t)(hop * 2 + 1) * BNc + mrow) * Hz];
            float4 f1a = *(const float4*)&f1p[((size_t)(hop * 2) * BNc + row) * Hz];
            float4 f1b = *(const float4*)&f1p[((size_t)(hop * 2 + 1) * BNc + row) * Hz];
            float e0v = (f1a.x + f1b.x) + (f2a.x + f2b.x);
            float e1v = (f1a.y + f1b.y) + (f2a.y + f2b.y);
            float e2v = (f1a.z + f1b.z) + (f2a.z + f2b.z);
            float e3v = (f1a.w + f1b.w) + (f2a.w + f2b.w);
            sat[0][t] = e0v >= 0.f ? e0v : 0.2f * e0v;
            sat[1][t] = e1v >= 0.f ? e1v : 0.2f * e1v;
            sat[2][t] = e2v >= 0.f ? e2v : 0.2f * e2v;
            sat[3][t] = e3v >= 0.f ? e3v : 0.2f * e3v;
        }
        __syncthreads();
        int h = t >> 5, j0 = t & 31;      // 32 threads per head
        float mx = -1e30f;
        for (int j = j0; j < deg; j += 32) mx = fmaxf(mx, sat[h][j]);
#pragma unroll
        for (int mm = 1; mm < 32; mm <<= 1) mx = fmaxf(mx, __shfl_xor(mx, mm));
        if (j0 == 0) red[h] = mx;
        __syncthreads();
        mx = red[h];
        float sum = 0.f;
        for (int j = j0; j < deg; j += 32) {
            float v = expf(sat[h][j] - mx);
            sat[h][j] = v;
            sum += v;
        }
#pragma unroll
        for (int mm = 1; mm < 32; mm <<= 1) sum += __shfl_xor(sum, mm);
        if (j0 == 0) red[4 + h] = 0.25f / sum;    // fold 1/Hz into the weights
        __syncthreads();
        float invh = red[4 + h];
        for (int j = j0; j < deg; j += 32) sat[h][j] *= invh;
        __syncthreads();
        float acc = 0.f;
        const unsigned short* wb = WhTb + t * 4;
        for (int j = 0; j < deg; j++) {
            int m = sidx[j];
            uint2 raw = *(const uint2*)(wb + (size_t)m * 512);
            acc += sat[0][j] * __uint_as_float(raw.x << 16)
                 + sat[1][j] * __uint_as_float(raw.x & 0xFFFF0000u)
                 + sat[2][j] * __uint_as_float(raw.y << 16)
                 + sat[3][j] * __uint_as_float(raw.y & 0xFFFF0000u);
        }
        G_a[((size_t)hop * BNc + row) * Dz + t] = acc;
    } else {
        // all-masked row: softmax of constant -9e15 = uniform 1/N over ALL m (JAX semantics)
        float acc = 0.f;
        const unsigned short* wb = WhTb + t * 4;
        for (int m = 0; m < Nz; m++) {
            uint2 raw = *(const uint2*)(wb + (size_t)m * 512);
            acc += __uint_as_float(raw.x << 16) + __uint_as_float(raw.x & 0xFFFF0000u)
                 + __uint_as_float(raw.y << 16) + __uint_as_float(raw.y & 0xFFFF0000u);
        }
        G_a[((size_t)hop * BNc + row) * Dz + t] = acc * (1.f / (Hz * Nz));
    }
}

// ---------------- fused hop: logits + softmax + u update (+ final out) --------------------
// one block per batch, 1024 threads (16 waves). A = G[hopA], Cm = G[hopA+1].
__global__ __launch_bounds__(1024) void k_hop(const float* __restrict__ G_a, int hopA,
                                              float* __restrict__ u, float* __restrict__ out,
                                              int last) {
    int b = blockIdx.x;
    int t = threadIdx.x;
    int wave = t >> 6, lane = t & 63;
    __shared__ float su[128];
    __shared__ float sl[1024];
    __shared__ float sp[1024];
    __shared__ float red[20];
    __shared__ float part[8][128];
    if (t < 128) su[t] = u[b * Dz + t];
    __syncthreads();
    const float* GA = G_a + ((size_t)hopA * BNc + ((size_t)b << 10)) * Dz;
    for (int i = 0; i < 64; i++) {        // logits: wave handles rows wave*64..+63
        int n = wave * 64 + i;
        const float* g = GA + (size_t)n * Dz;
        float s = g[lane] * su[lane] + g[lane + 64] * su[lane + 64];
#pragma unroll
        for (int off = 32; off; off >>= 1) s += __shfl_down(s, off);
        if (lane == 0) sl[n] = s;
    }
    __syncthreads();
    float v = sl[t];
    float mx = v;
#pragma unroll
    for (int off = 32; off; off >>= 1) mx = fmaxf(mx, __shfl_down(mx, off));
    if (lane == 0) red[wave] = mx;
    __syncthreads();
    if (t == 0) {
        float m = red[0];
        for (int i = 1; i < 16; i++) m = fmaxf(m, red[i]);
        red[16] = m;
    }
    __syncthreads();
    mx = red[16];
    float e = expf(v - mx);
    float s = e;
#pragma unroll
    for (int off = 32; off; off >>= 1) s += __shfl_down(s, off);
    if (lane == 0) red[wave] = s;
    __syncthreads();
    if (t == 0) {
        float ss = 0.f;
        for (int i = 0; i < 16; i++) ss += red[i];
        red[17] = 1.f / ss;
    }
    __syncthreads();
    sp[t] = e * red[17];
    __syncthreads();
    // u update: u[b,d] += sum_n Cm[b,n,d] * p[n]
    const float* GC = G_a + ((size_t)(hopA + 1) * BNc + ((size_t)b << 10)) * Dz;
    int d = t & 127, chunk = t >> 7;
    float acc = 0.f;
    const float* gc = GC + (size_t)chunk * 128 * Dz + d;
    const float* pc = &sp[chunk * 128];
    for (int j = 0; j < 128; j++) acc += gc[(size_t)j * Dz] * pc[j];
    part[chunk][d] = acc;
    __syncthreads();
    if (t < 128) {
        float un = su[t];
        for (int c = 0; c < 8; c++) un += part[c][t];
        u[b * Dz + t] = un;
        if (last) out[Bz * Nz + b * Dz + t] = un;
    }
    if (last) {
        float l = sl[t];
        out[b * Nz + t] = 1.f / (1.f + expf(-l));
        out[Bz * Nz + Bz * Dz + b * Nz + t] = l;
    }
}

// ---------------- host ---------------------------------------------------------------------
extern "C" void kernel_launch(void* const* d_in, const int* in_sizes, int n_in,
                              void* d_out, int out_size, void* d_ws, size_t ws_size,
                              hipStream_t stream) {
    const int*   story    = (const int*)d_in[0];
    const int*   kb_len   = (const int*)d_in[1];
    const int*   conv_len = (const int*)d_in[2];
    const float* hidden   = (const float*)d_in[3];
    const float* dh       = (const float*)d_in[4];
    const float* adj      = (const float*)d_in[5];
    const float* emb      = (const float*)d_in[6];
    const float* gat_W    = (const float*)d_in[7];
    const float* gat_a    = (const float*)d_in[8];
    float* out = (float*)d_out;

    char* w = (char*)d_ws;
    auto alloc = [&](size_t bytes) {
        char* pp = w;
        w += (bytes + 255) & ~(size_t)255;
        return pp;
    };
    const size_t BN = (size_t)Bz * Nz;
    int*            idx  = (int*)           alloc(BN * CAP * 4);          // 8.4 MB
    int*            cnt  = (int*)           alloc(BN * 4);
    unsigned short* xhi  = (unsigned short*)alloc(4 * BN * Dz * 2);       // 16.8 MB
    unsigned short* xlo  = (unsigned short*)alloc(4 * BN * Dz * 2);
    unsigned short* wthi = (unsigned short*)alloc(4 * Hz * Dz * Dz * 2);
    unsigned short* wtlo = (unsigned short*)alloc(4 * Hz * Dz * Dz * 2);
    unsigned short* WhT  = (unsigned short*)alloc(4 * BN * Hz * Dz * 2);  // 67 MB
    float*          f1p  = (float*)         alloc(8 * BN * Hz * 4);
    float*          f2p  = (float*)         alloc(8 * BN * Hz * 4);
    float*          G    = (float*)         alloc(4 * BN * Dz * 4);       // 33.6 MB
    float*          u    = (float*)         alloc((size_t)Bz * Dz * 4);

    k_prep<<<BNc + 1024 + 8, 256, 0, stream>>>(adj, kb_len, conv_len, gat_W, hidden,
                                               idx, cnt, wthi, wtlo, u);
    k_embed4<<<BNc, 128, 0, stream>>>(story, emb, dh, kb_len, conv_len, xhi, xlo);
    k_whf4<<<dim3(8, 128, 4), 256, 0, stream>>>(xhi, xlo, wthi, wtlo, gat_a, WhT, f1p, f2p);
    k_attn4<<<4 * BNc, 128, 0, stream>>>(WhT, f1p, f2p, idx, cnt, G);
    k_hop<<<Bz, 1024, 0, stream>>>(G, 0, u, out, 0);
    k_hop<<<Bz, 1024, 0, stream>>>(G, 1, u, out, 0);
    k_hop<<<Bz, 1024, 0, stream>>>(G, 2, u, out, 1);
}

// Round 6
// 433.031 us; speedup vs baseline: 1.6187x; 1.1086x over previous
//
#include <hip/hip_runtime.h>
#include <hip/hip_bf16.h>
#include <math.h>

#define Bz 16
#define Nz 1024
#define Mz 4
#define Dz 128
#define Hz 4
#define VOCABz 32000
#define CAP 128
#define BNc (Bz * Nz)
#define NC 576            // 512 Wh cols (e*4+h) + 8 f-cols + 56 pad

typedef __attribute__((ext_vector_type(8))) short bf16x8;
typedef __attribute__((ext_vector_type(4))) float f32x4;
typedef __attribute__((ext_vector_type(2))) _Float16 f16x2;

#if defined(__has_builtin)
#if __has_builtin(__builtin_amdgcn_fdot2)
#define FDOT2(w, s, acc) acc = __builtin_amdgcn_fdot2((w), (s), (acc), false)
#endif
#endif
#ifndef FDOT2
#define FDOT2(w, s, acc) acc += (float)(w)[0] * (float)(s)[0] + (float)(w)[1] * (float)(s)[1]
#endif

__device__ inline unsigned short rne_bf16(float x) {
    unsigned u = __float_as_uint(x);
    unsigned r = (u + 0x7FFFu + ((u >> 16) & 1u)) >> 16;
    return (unsigned short)r;
}
__device__ inline float bf16_to_f(unsigned short h) {
    return __uint_as_float(((unsigned)h) << 16);
}
__device__ inline unsigned short f32_to_f16_bits(float x) {
    _Float16 hv = (_Float16)x;
    return __builtin_bit_cast(unsigned short, hv);
}

// ---------------- prep: CSR (blocks <BNc) + Wcat split (1152 blocks) + uinit --------------
// Wcat[hop][c][d]: c<512 -> W[hop][h=c&3][d][e=c>>2]; c in [512,520): q=c-512,
//   col = sum_e W[hop][h=q&3][d][e] * a[hop][h][ (q>>2)*128 + e ]; c>=520 -> 0.
__global__ __launch_bounds__(256) void k_prep(const float* __restrict__ adj,
                                              const int* __restrict__ kb_len,
                                              const int* __restrict__ conv_len,
                                              const float* __restrict__ gat_W,
                                              const float* __restrict__ gat_a,
                                              const float* __restrict__ hidden,
                                              int* __restrict__ idx, int* __restrict__ cnt,
                                              unsigned short* __restrict__ wthi,
                                              unsigned short* __restrict__ wtlo,
                                              float* __restrict__ u) {
    int blk = blockIdx.x;
    int t = threadIdx.x;
    if (blk < BNc) {                      // CSR row
        int row = blk;
        int b = row >> 10, n = row & 1023;
        __shared__ int scnt;
        if (t == 0) scnt = 0;
        __syncthreads();
        int ctx = kb_len[b] + conv_len[b];
        const float4 av = *((const float4*)(adj + (size_t)row * Nz) + t);
        int m0 = t * 4;
#pragma unroll
        for (int k = 0; k < 4; k++) {
            float a = k == 0 ? av.x : k == 1 ? av.y : k == 2 ? av.z : av.w;
            int m = m0 + k;
            bool on = (a > 0.f) || (m == n && n >= ctx);
            if (on) {
                int p = atomicAdd(&scnt, 1);
                if (p < CAP) idx[(size_t)row * CAP + p] = m;
            }
        }
        __syncthreads();
        if (t == 0) cnt[row] = scnt < CAP ? scnt : CAP;
    } else if (blk < BNc + 1152) {        // Wcat split: 4*576*128 elems
        int i = (blk - BNc) * 256 + t;
        int d = i & 127;
        int rest = i >> 7;                // hop*576 + c
        int c = rest % NC;
        int hop = rest / NC;
        float v;
        if (c < 512) {
            int h = c & 3, e = c >> 2;
            v = gat_W[(((size_t)(hop * 4 + h)) * 128 + d) * 128 + e];
        } else if (c < 520) {
            int q = c - 512;
            int h = q & 3, which = q >> 2;
            const float* wrow = gat_W + (((size_t)(hop * 4 + h)) * 128 + d) * 128;
            const float* arow = gat_a + ((size_t)(hop * 4 + h)) * 256 + which * 128;
            float s = 0.f;
            for (int e = 0; e < 128; e++) s += wrow[e] * arow[e];
            v = s;
        } else {
            v = 0.f;
        }
        unsigned short h = rne_bf16(v);
        wthi[i] = h;
        wtlo[i] = rne_bf16(v - bf16_to_f(h));
    } else {                              // u init
        int i = (blk - BNc - 1152) * 256 + t;
        if (i < Bz * Dz) u[i] = hidden[i];
    }
}

// ---------------- embed all 4 hops: x = sum emb rows (+ dh), split to bf16 hi/lo ----------
__global__ __launch_bounds__(128) void k_embed4(const int* __restrict__ story,
                                                const float* __restrict__ emb,
                                                const float* __restrict__ dh,
                                                const int* __restrict__ kb_len,
                                                const int* __restrict__ conv_len,
                                                unsigned short* __restrict__ xhi,
                                                unsigned short* __restrict__ xlo) {
    int row = blockIdx.x;                 // b*N + n
    int b = row >> 10, n = row & 1023;
    int d = threadIdx.x;                  // 128
    const int* st = story + (size_t)row * Mz;
    int s0 = st[0], s1 = st[1], s2 = st[2], s3 = st[3];
    int rel = n - (kb_len[b] - 1);
    float dhv = (rel >= 0 && rel < conv_len[b]) ? dh[((size_t)(b << 10) + rel) * Dz + d] : 0.f;
#pragma unroll
    for (int hop = 0; hop < 4; hop++) {
        const float* ek = emb + (size_t)hop * VOCABz * Dz;
        float acc = ek[(size_t)s0 * Dz + d] + ek[(size_t)s1 * Dz + d]
                  + ek[(size_t)s2 * Dz + d] + ek[(size_t)s3 * Dz + d] + dhv;
        unsigned short hb = rne_bf16(acc);
        size_t o = (size_t)hop * BNc * Dz + (size_t)row * Dz + d;
        xhi[o] = hb;
        xlo[o] = rne_bf16(acc - bf16_to_f(hb));
    }
}

// ---------------- GEMM X@Wcat (bf16x3 MFMA): WhT f16 [hop][row][c], ff fp32 [hop][row][8] --
// 4608 blocks: xcd=blk&7, s=blk>>3: hop=s/144, rt_loc=(s%144)/9, ctile=s%9.
// rowtile = xcd*16+rt_loc -> 9 consecutive per-XCD blocks share one X rowtile (L2 reuse).
#define AST 72
__global__ __launch_bounds__(256) void k_whf4(const unsigned short* __restrict__ xhi_a,
                                              const unsigned short* __restrict__ xlo_a,
                                              const unsigned short* __restrict__ wthi_a,
                                              const unsigned short* __restrict__ wtlo_a,
                                              unsigned short* __restrict__ WhT_a,
                                              float* __restrict__ ff) {
    int blk = blockIdx.x;
    int xcd = blk & 7;
    int s = blk >> 3;
    int hop = s / 144;
    int r = s - hop * 144;
    int rt = r / 9;
    int ct = r - rt * 9;
    int row0 = (xcd * 16 + rt) * 128;
    int t = threadIdx.x;
    int wave = t >> 6, lane = t & 63;
    int quad = lane >> 4, l16 = lane & 15;

    const unsigned short* xhi = xhi_a + (size_t)hop * BNc * Dz;
    const unsigned short* xlo = xlo_a + (size_t)hop * BNc * Dz;
    const unsigned short* wthi = wthi_a + (size_t)hop * NC * 128;
    const unsigned short* wtlo = wtlo_a + (size_t)hop * NC * 128;

    __shared__ unsigned short Ah[128 * AST], Al[128 * AST];   // X tile hi/lo [r][k]
    __shared__ unsigned short Bh[64 * AST], Bl[64 * AST];     // Wcat tile hi/lo [c][d]

    f32x4 acc[2][4];
#pragma unroll
    for (int mt = 0; mt < 2; mt++)
#pragma unroll
        for (int nt = 0; nt < 4; nt++) acc[mt][nt] = (f32x4)0.f;

    for (int ph = 0; ph < 2; ph++) {
        int kb = ph * 64;
        for (int i = t; i < 1024; i += 256) {
            int rr = i >> 3, c = (i & 7) * 8;
            *(uint4*)&Ah[rr * AST + c] = *(const uint4*)&xhi[(size_t)(row0 + rr) * Dz + kb + c];
            *(uint4*)&Al[rr * AST + c] = *(const uint4*)&xlo[(size_t)(row0 + rr) * Dz + kb + c];
        }
        for (int i = t; i < 512; i += 256) {
            int cr = i >> 3, cc = (i & 7) * 8;
            size_t src = ((size_t)(ct * 64 + cr)) * 128 + kb + cc;
            *(uint4*)&Bh[cr * AST + cc] = *(const uint4*)&wthi[src];
            *(uint4*)&Bl[cr * AST + cc] = *(const uint4*)&wtlo[src];
        }
        __syncthreads();
#pragma unroll
        for (int ks = 0; ks < 2; ks++) {
            int ko = ks * 32 + quad * 8;
            bf16x8 ah[2], al[2];
#pragma unroll
            for (int mt = 0; mt < 2; mt++) {
                int rr = wave * 32 + mt * 16 + l16;
                ah[mt] = *(const bf16x8*)&Ah[rr * AST + ko];
                al[mt] = *(const bf16x8*)&Al[rr * AST + ko];
            }
#pragma unroll
            for (int nt = 0; nt < 4; nt++) {
                int cc = nt * 16 + l16;
                bf16x8 bh = *(const bf16x8*)&Bh[cc * AST + ko];
                bf16x8 bl = *(const bf16x8*)&Bl[cc * AST + ko];
#pragma unroll
                for (int mt = 0; mt < 2; mt++) {
                    acc[mt][nt] = __builtin_amdgcn_mfma_f32_16x16x32_bf16(ah[mt], bh, acc[mt][nt], 0, 0, 0);
                    acc[mt][nt] = __builtin_amdgcn_mfma_f32_16x16x32_bf16(ah[mt], bl, acc[mt][nt], 0, 0, 0);
                    acc[mt][nt] = __builtin_amdgcn_mfma_f32_16x16x32_bf16(al[mt], bh, acc[mt][nt], 0, 0, 0);
                }
            }
        }
        __syncthreads();
    }

    if (ct < 8) {
        // repack 128x64 f16 tile through LDS (alias Ah), then coalesced uint4 stores
        unsigned short* St = Ah;          // stride AST=72, 128*72 shorts fits Ah
#pragma unroll
        for (int mt = 0; mt < 2; mt++)
#pragma unroll
            for (int nt = 0; nt < 4; nt++)
#pragma unroll
                for (int reg = 0; reg < 4; reg++) {
                    int rr = wave * 32 + mt * 16 + quad * 4 + reg;
                    int cc = nt * 16 + l16;
                    St[rr * AST + cc] = f32_to_f16_bits(acc[mt][nt][reg]);
                }
        __syncthreads();
        int rr = t >> 1, seg = t & 1;
        size_t gbase = ((size_t)hop * BNc + row0 + rr) * 512 + ct * 64 + seg * 32;
#pragma unroll
        for (int k = 0; k < 4; k++) {
            uint4 vv = *(uint4*)&St[rr * AST + seg * 32 + k * 8];
            *(uint4*)&WhT_a[gbase + k * 8] = vv;
        }
    } else {
        // f-columns: c = 512+q, q<8 -> ff[hop][row][q]  (only nt==0, l16<8 lanes)
        if (l16 < 8) {
#pragma unroll
            for (int mt = 0; mt < 2; mt++)
#pragma unroll
                for (int reg = 0; reg < 4; reg++) {
                    int row = row0 + wave * 32 + mt * 16 + quad * 4 + reg;
                    ff[((size_t)hop * BNc + row) * 8 + l16] = acc[mt][0][reg];
                }
        }
    }
}

// ---------------- sparse GAT attention for all hops (f16 dot2 inner loop) -----------------
__global__ __launch_bounds__(128) void k_attn4(const unsigned short* __restrict__ WhT_a,
                                               const float* __restrict__ ff,
                                               const int* __restrict__ idx,
                                               const int* __restrict__ cnt,
                                               float* __restrict__ G_a) {
    int blk = blockIdx.x;
    int xcd = blk & 7;
    int s = blk >> 3;                     // 0..8191
    int pair = s >> 7;                    // 0..63
    int hop = pair >> 4;
    int b = pair & 15;
    int n = ((s & 127) << 3) | xcd;
    int row = (b << 10) | n;
    int t = threadIdx.x;                  // 128
    __shared__ int sidx[CAP];
    __shared__ float sat[Hz][CAP];
    __shared__ f16x2 sp01[CAP], sp23[CAP];
    __shared__ float red[8];
    int deg = cnt[row];
    const unsigned short* WhTb = WhT_a + ((size_t)hop * BNc + ((size_t)b << 10)) * 512;
    const float* ffh = ff + (size_t)hop * BNc * 8;
    if (deg > 0) {
        if (t < deg) {
            int m = idx[(size_t)row * CAP + t];
            sidx[t] = m;
            int mrow = (b << 10) | m;
            float4 f1r = *(const float4*)&ffh[(size_t)row * 8];
            float4 f2m = *(const float4*)&ffh[(size_t)mrow * 8 + 4];
            float e0v = f1r.x + f2m.x;
            float e1v = f1r.y + f2m.y;
            float e2v = f1r.z + f2m.z;
            float e3v = f1r.w + f2m.w;
            sat[0][t] = e0v >= 0.f ? e0v : 0.2f * e0v;
            sat[1][t] = e1v >= 0.f ? e1v : 0.2f * e1v;
            sat[2][t] = e2v >= 0.f ? e2v : 0.2f * e2v;
            sat[3][t] = e3v >= 0.f ? e3v : 0.2f * e3v;
        }
        __syncthreads();
        int h = t >> 5, j0 = t & 31;      // 32 threads per head
        float mx = -1e30f;
        for (int j = j0; j < deg; j += 32) mx = fmaxf(mx, sat[h][j]);
#pragma unroll
        for (int mm = 1; mm < 32; mm <<= 1) mx = fmaxf(mx, __shfl_xor(mx, mm));
        if (j0 == 0) red[h] = mx;
        __syncthreads();
        mx = red[h];
        float sum = 0.f;
        for (int j = j0; j < deg; j += 32) {
            float v = expf(sat[h][j] - mx);
            sat[h][j] = v;
            sum += v;
        }
#pragma unroll
        for (int mm = 1; mm < 32; mm <<= 1) sum += __shfl_xor(sum, mm);
        if (j0 == 0) red[4 + h] = 0.25f / sum;    // fold 1/Hz into the weights
        __syncthreads();
        if (t < deg) {                    // scale + pack to f16 pairs
            float s0 = sat[0][t] * red[4];
            float s1 = sat[1][t] * red[5];
            float s2 = sat[2][t] * red[6];
            float s3 = sat[3][t] * red[7];
            f16x2 p01, p23;
            p01[0] = (_Float16)s0; p01[1] = (_Float16)s1;
            p23[0] = (_Float16)s2; p23[1] = (_Float16)s3;
            sp01[t] = p01;
            sp23[t] = p23;
        }
        __syncthreads();
        float acc = 0.f;
        const unsigned short* wb = WhTb + t * 4;
        for (int j = 0; j < deg; j++) {
            int m = sidx[j];
            uint2 raw = *(const uint2*)(wb + (size_t)m * 512);
            f16x2 w01 = __builtin_bit_cast(f16x2, raw.x);
            f16x2 w23 = __builtin_bit_cast(f16x2, raw.y);
            FDOT2(w01, sp01[j], acc);
            FDOT2(w23, sp23[j], acc);
        }
        G_a[((size_t)hop * BNc + row) * Dz + t] = acc;
    } else {
        // all-masked row: softmax of constant -9e15 = uniform 1/N over ALL m (JAX semantics)
        float acc = 0.f;
        const unsigned short* wb = WhTb + t * 4;
        for (int m = 0; m < Nz; m++) {
            uint2 raw = *(const uint2*)(wb + (size_t)m * 512);
            f16x2 w01 = __builtin_bit_cast(f16x2, raw.x);
            f16x2 w23 = __builtin_bit_cast(f16x2, raw.y);
            acc += (float)w01[0] + (float)w01[1] + (float)w23[0] + (float)w23[1];
        }
        G_a[((size_t)hop * BNc + row) * Dz + t] = acc * (1.f / (Hz * Nz));
    }
}

// ---------------- fused hop: logits + softmax + u update (+ final out) --------------------
__global__ __launch_bounds__(1024) void k_hop(const float* __restrict__ G_a, int hopA,
                                              float* __restrict__ u, float* __restrict__ out,
                                              int last) {
    int b = blockIdx.x;
    int t = threadIdx.x;
    int wave = t >> 6, lane = t & 63;
    __shared__ float su[128];
    __shared__ float sl[1024];
    __shared__ float sp[1024];
    __shared__ float red[20];
    __shared__ float part[8][128];
    if (t < 128) su[t] = u[b * Dz + t];
    __syncthreads();
    const float* GA = G_a + ((size_t)hopA * BNc + ((size_t)b << 10)) * Dz;
    for (int i = 0; i < 64; i++) {
        int n = wave * 64 + i;
        const float* g = GA + (size_t)n * Dz;
        float s = g[lane] * su[lane] + g[lane + 64] * su[lane + 64];
#pragma unroll
        for (int off = 32; off; off >>= 1) s += __shfl_down(s, off);
        if (lane == 0) sl[n] = s;
    }
    __syncthreads();
    float v = sl[t];
    float mx = v;
#pragma unroll
    for (int off = 32; off; off >>= 1) mx = fmaxf(mx, __shfl_down(mx, off));
    if (lane == 0) red[wave] = mx;
    __syncthreads();
    if (t == 0) {
        float m = red[0];
        for (int i = 1; i < 16; i++) m = fmaxf(m, red[i]);
        red[16] = m;
    }
    __syncthreads();
    mx = red[16];
    float e = expf(v - mx);
    float s = e;
#pragma unroll
    for (int off = 32; off; off >>= 1) s += __shfl_down(s, off);
    if (lane == 0) red[wave] = s;
    __syncthreads();
    if (t == 0) {
        float ss = 0.f;
        for (int i = 0; i < 16; i++) ss += red[i];
        red[17] = 1.f / ss;
    }
    __syncthreads();
    sp[t] = e * red[17];
    __syncthreads();
    const float* GC = G_a + ((size_t)(hopA + 1) * BNc + ((size_t)b << 10)) * Dz;
    int d = t & 127, chunk = t >> 7;
    float acc = 0.f;
    const float* gc = GC + (size_t)chunk * 128 * Dz + d;
    const float* pc = &sp[chunk * 128];
    for (int j = 0; j < 128; j++) acc += gc[(size_t)j * Dz] * pc[j];
    part[chunk][d] = acc;
    __syncthreads();
    if (t < 128) {
        float un = su[t];
        for (int c = 0; c < 8; c++) un += part[c][t];
        u[b * Dz + t] = un;
        if (last) out[Bz * Nz + b * Dz + t] = un;
    }
    if (last) {
        float l = sl[t];
        out[b * Nz + t] = 1.f / (1.f + expf(-l));
        out[Bz * Nz + Bz * Dz + b * Nz + t] = l;
    }
}

// ---------------- host ---------------------------------------------------------------------
extern "C" void kernel_launch(void* const* d_in, const int* in_sizes, int n_in,
                              void* d_out, int out_size, void* d_ws, size_t ws_size,
                              hipStream_t stream) {
    const int*   story    = (const int*)d_in[0];
    const int*   kb_len   = (const int*)d_in[1];
    const int*   conv_len = (const int*)d_in[2];
    const float* hidden   = (const float*)d_in[3];
    const float* dh       = (const float*)d_in[4];
    const float* adj      = (const float*)d_in[5];
    const float* emb      = (const float*)d_in[6];
    const float* gat_W    = (const float*)d_in[7];
    const float* gat_a    = (const float*)d_in[8];
    float* out = (float*)d_out;

    char* w = (char*)d_ws;
    auto alloc = [&](size_t bytes) {
        char* pp = w;
        w += (bytes + 255) & ~(size_t)255;
        return pp;
    };
    const size_t BN = (size_t)Bz * Nz;
    int*            idx  = (int*)           alloc(BN * CAP * 4);          // 8.4 MB
    int*            cnt  = (int*)           alloc(BN * 4);
    unsigned short* xhi  = (unsigned short*)alloc(4 * BN * Dz * 2);       // 16.8 MB
    unsigned short* xlo  = (unsigned short*)alloc(4 * BN * Dz * 2);
    unsigned short* wthi = (unsigned short*)alloc(4 * NC * 128 * 2);      // 0.6 MB
    unsigned short* wtlo = (unsigned short*)alloc(4 * NC * 128 * 2);
    unsigned short* WhT  = (unsigned short*)alloc(4 * BN * 512 * 2);      // 67 MB
    float*          ff   = (float*)         alloc(4 * BN * 8 * 4);        // 2.1 MB
    float*          G    = (float*)         alloc(4 * BN * Dz * 4);       // 33.6 MB
    float*          u    = (float*)         alloc((size_t)Bz * Dz * 4);

    k_prep<<<BNc + 1152 + 8, 256, 0, stream>>>(adj, kb_len, conv_len, gat_W, gat_a, hidden,
                                               idx, cnt, wthi, wtlo, u);
    k_embed4<<<BNc, 128, 0, stream>>>(story, emb, dh, kb_len, conv_len, xhi, xlo);
    k_whf4<<<4608, 256, 0, stream>>>(xhi, xlo, wthi, wtlo, WhT, ff);
    k_attn4<<<4 * BNc, 128, 0, stream>>>(WhT, ff, idx, cnt, G);
    k_hop<<<Bz, 1024, 0, stream>>>(G, 0, u, out, 0);
    k_hop<<<Bz, 1024, 0, stream>>>(G, 1, u, out, 0);
    k_hop<<<Bz, 1024, 0, stream>>>(G, 2, u, out, 1);
}

// Round 7
// 366.955 us; speedup vs baseline: 1.9102x; 1.1801x over previous
//
#include <hip/hip_runtime.h>
#include <hip/hip_bf16.h>
#include <math.h>

#define Bz 16
#define Nz 1024
#define Mz 4
#define Dz 128
#define Hz 4
#define VOCABz 32000
#define CAP 128
#define BNc (Bz * Nz)
#define NC 576            // 512 Wh cols (e*4+h) + 8 f-cols + 56 pad

typedef __attribute__((ext_vector_type(8))) short bf16x8;
typedef __attribute__((ext_vector_type(4))) float f32x4;
typedef __attribute__((ext_vector_type(2))) _Float16 f16x2;

#if defined(__has_builtin)
#if __has_builtin(__builtin_amdgcn_fdot2)
#define FDOT2(w, s, acc) acc = __builtin_amdgcn_fdot2((w), (s), (acc), false)
#endif
#endif
#ifndef FDOT2
#define FDOT2(w, s, acc) acc += (float)(w)[0] * (float)(s)[0] + (float)(w)[1] * (float)(s)[1]
#endif

__device__ inline unsigned short rne_bf16(float x) {
    unsigned u = __float_as_uint(x);
    unsigned r = (u + 0x7FFFu + ((u >> 16) & 1u)) >> 16;
    return (unsigned short)r;
}
__device__ inline float bf16_to_f(unsigned short h) {
    return __uint_as_float(((unsigned)h) << 16);
}
__device__ inline unsigned short f32_to_f16_bits(float x) {
    _Float16 hv = (_Float16)x;
    return __builtin_bit_cast(unsigned short, hv);
}

// ---------------- prep: CSR (blocks <BNc) + Wcat split (1152 blocks) + uinit --------------
__global__ __launch_bounds__(256) void k_prep(const float* __restrict__ adj,
                                              const int* __restrict__ kb_len,
                                              const int* __restrict__ conv_len,
                                              const float* __restrict__ gat_W,
                                              const float* __restrict__ gat_a,
                                              const float* __restrict__ hidden,
                                              int* __restrict__ idx, int* __restrict__ cnt,
                                              unsigned short* __restrict__ wthi,
                                              unsigned short* __restrict__ wtlo,
                                              float* __restrict__ u) {
    int blk = blockIdx.x;
    int t = threadIdx.x;
    if (blk < BNc) {                      // CSR row
        int row = blk;
        int b = row >> 10, n = row & 1023;
        __shared__ int scnt;
        if (t == 0) scnt = 0;
        __syncthreads();
        int ctx = kb_len[b] + conv_len[b];
        const float4 av = *((const float4*)(adj + (size_t)row * Nz) + t);
        int m0 = t * 4;
#pragma unroll
        for (int k = 0; k < 4; k++) {
            float a = k == 0 ? av.x : k == 1 ? av.y : k == 2 ? av.z : av.w;
            int m = m0 + k;
            bool on = (a > 0.f) || (m == n && n >= ctx);
            if (on) {
                int p = atomicAdd(&scnt, 1);
                if (p < CAP) idx[(size_t)row * CAP + p] = m;
            }
        }
        __syncthreads();
        if (t == 0) cnt[row] = scnt < CAP ? scnt : CAP;
    } else if (blk < BNc + 1152) {        // Wcat split: 4*576*128 elems
        int i = (blk - BNc) * 256 + t;
        int d = i & 127;
        int rest = i >> 7;                // hop*576 + c
        int c = rest % NC;
        int hop = rest / NC;
        float v;
        if (c < 512) {
            int h = c & 3, e = c >> 2;
            v = gat_W[(((size_t)(hop * 4 + h)) * 128 + d) * 128 + e];
        } else if (c < 520) {
            int q = c - 512;
            int h = q & 3, which = q >> 2;
            const float* wrow = gat_W + (((size_t)(hop * 4 + h)) * 128 + d) * 128;
            const float* arow = gat_a + ((size_t)(hop * 4 + h)) * 256 + which * 128;
            float s = 0.f;
            for (int e = 0; e < 128; e++) s += wrow[e] * arow[e];
            v = s;
        } else {
            v = 0.f;
        }
        unsigned short h = rne_bf16(v);
        wthi[i] = h;
        wtlo[i] = rne_bf16(v - bf16_to_f(h));
    } else {                              // u init
        int i = (blk - BNc - 1152) * 256 + t;
        if (i < Bz * Dz) u[i] = hidden[i];
    }
}

// ---------------- embed all 4 hops: x = sum emb rows (+ dh), split to bf16 hi/lo ----------
__global__ __launch_bounds__(128) void k_embed4(const int* __restrict__ story,
                                                const float* __restrict__ emb,
                                                const float* __restrict__ dh,
                                                const int* __restrict__ kb_len,
                                                const int* __restrict__ conv_len,
                                                unsigned short* __restrict__ xhi,
                                                unsigned short* __restrict__ xlo) {
    int row = blockIdx.x;                 // b*N + n
    int b = row >> 10, n = row & 1023;
    int d = threadIdx.x;                  // 128
    const int* st = story + (size_t)row * Mz;
    int s0 = st[0], s1 = st[1], s2 = st[2], s3 = st[3];
    int rel = n - (kb_len[b] - 1);
    float dhv = (rel >= 0 && rel < conv_len[b]) ? dh[((size_t)(b << 10) + rel) * Dz + d] : 0.f;
#pragma unroll
    for (int hop = 0; hop < 4; hop++) {
        const float* ek = emb + (size_t)hop * VOCABz * Dz;
        float acc = ek[(size_t)s0 * Dz + d] + ek[(size_t)s1 * Dz + d]
                  + ek[(size_t)s2 * Dz + d] + ek[(size_t)s3 * Dz + d] + dhv;
        unsigned short hb = rne_bf16(acc);
        size_t o = (size_t)hop * BNc * Dz + (size_t)row * Dz + d;
        xhi[o] = hb;
        xlo[o] = rne_bf16(acc - bf16_to_f(hb));
    }
}

// ---------------- GEMM X@Wcat (bf16x3 MFMA): WhT f16 [hop][row][c], ff fp32 [hop][row][8] --
#define AST 72
__global__ __launch_bounds__(256) void k_whf4(const unsigned short* __restrict__ xhi_a,
                                              const unsigned short* __restrict__ xlo_a,
                                              const unsigned short* __restrict__ wthi_a,
                                              const unsigned short* __restrict__ wtlo_a,
                                              unsigned short* __restrict__ WhT_a,
                                              float* __restrict__ ff) {
    int blk = blockIdx.x;
    int xcd = blk & 7;
    int s = blk >> 3;
    int hop = s / 144;
    int r = s - hop * 144;
    int rt = r / 9;
    int ct = r - rt * 9;
    int row0 = (xcd * 16 + rt) * 128;
    int t = threadIdx.x;
    int wave = t >> 6, lane = t & 63;
    int quad = lane >> 4, l16 = lane & 15;

    const unsigned short* xhi = xhi_a + (size_t)hop * BNc * Dz;
    const unsigned short* xlo = xlo_a + (size_t)hop * BNc * Dz;
    const unsigned short* wthi = wthi_a + (size_t)hop * NC * 128;
    const unsigned short* wtlo = wtlo_a + (size_t)hop * NC * 128;

    __shared__ unsigned short Ah[128 * AST], Al[128 * AST];   // X tile hi/lo [r][k]
    __shared__ unsigned short Bh[64 * AST], Bl[64 * AST];     // Wcat tile hi/lo [c][d]

    f32x4 acc[2][4];
#pragma unroll
    for (int mt = 0; mt < 2; mt++)
#pragma unroll
        for (int nt = 0; nt < 4; nt++) acc[mt][nt] = (f32x4)0.f;

    for (int ph = 0; ph < 2; ph++) {
        int kb = ph * 64;
        for (int i = t; i < 1024; i += 256) {
            int rr = i >> 3, c = (i & 7) * 8;
            *(uint4*)&Ah[rr * AST + c] = *(const uint4*)&xhi[(size_t)(row0 + rr) * Dz + kb + c];
            *(uint4*)&Al[rr * AST + c] = *(const uint4*)&xlo[(size_t)(row0 + rr) * Dz + kb + c];
        }
        for (int i = t; i < 512; i += 256) {
            int cr = i >> 3, cc = (i & 7) * 8;
            size_t src = ((size_t)(ct * 64 + cr)) * 128 + kb + cc;
            *(uint4*)&Bh[cr * AST + cc] = *(const uint4*)&wthi[src];
            *(uint4*)&Bl[cr * AST + cc] = *(const uint4*)&wtlo[src];
        }
        __syncthreads();
#pragma unroll
        for (int ks = 0; ks < 2; ks++) {
            int ko = ks * 32 + quad * 8;
            bf16x8 ah[2], al[2];
#pragma unroll
            for (int mt = 0; mt < 2; mt++) {
                int rr = wave * 32 + mt * 16 + l16;
                ah[mt] = *(const bf16x8*)&Ah[rr * AST + ko];
                al[mt] = *(const bf16x8*)&Al[rr * AST + ko];
            }
#pragma unroll
            for (int nt = 0; nt < 4; nt++) {
                int cc = nt * 16 + l16;
                bf16x8 bh = *(const bf16x8*)&Bh[cc * AST + ko];
                bf16x8 bl = *(const bf16x8*)&Bl[cc * AST + ko];
#pragma unroll
                for (int mt = 0; mt < 2; mt++) {
                    acc[mt][nt] = __builtin_amdgcn_mfma_f32_16x16x32_bf16(ah[mt], bh, acc[mt][nt], 0, 0, 0);
                    acc[mt][nt] = __builtin_amdgcn_mfma_f32_16x16x32_bf16(ah[mt], bl, acc[mt][nt], 0, 0, 0);
                    acc[mt][nt] = __builtin_amdgcn_mfma_f32_16x16x32_bf16(al[mt], bh, acc[mt][nt], 0, 0, 0);
                }
            }
        }
        __syncthreads();
    }

    if (ct < 8) {
        // repack 128x64 f16 tile through LDS (alias Ah), then coalesced uint4 stores
        unsigned short* St = Ah;          // stride AST=72, 128*72 shorts fits Ah
#pragma unroll
        for (int mt = 0; mt < 2; mt++)
#pragma unroll
            for (int nt = 0; nt < 4; nt++)
#pragma unroll
                for (int reg = 0; reg < 4; reg++) {
                    int rr = wave * 32 + mt * 16 + quad * 4 + reg;
                    int cc = nt * 16 + l16;
                    St[rr * AST + cc] = f32_to_f16_bits(acc[mt][nt][reg]);
                }
        __syncthreads();
        int rr = t >> 1, seg = t & 1;
        size_t gbase = ((size_t)hop * BNc + row0 + rr) * 512 + ct * 64 + seg * 32;
#pragma unroll
        for (int k = 0; k < 4; k++) {
            uint4 vv = *(uint4*)&St[rr * AST + seg * 32 + k * 8];
            *(uint4*)&WhT_a[gbase + k * 8] = vv;
        }
    } else {
        // f-columns: c = 512+q, q<8 -> ff[hop][row][q]  (only nt==0, l16<8 lanes)
        if (l16 < 8) {
#pragma unroll
            for (int mt = 0; mt < 2; mt++)
#pragma unroll
                for (int reg = 0; reg < 4; reg++) {
                    int row = row0 + wave * 32 + mt * 16 + quad * 4 + reg;
                    ff[((size_t)hop * BNc + row) * 8 + l16] = acc[mt][0][reg];
                }
        }
    }
}

// ---------------- sparse GAT attention for all hops (f16 dot2 inner loop) -----------------
// pair-per-XCD swizzle: pair p=hop*16+b owned by XCD p&7; blk=((p>>3)*1024+n)*8+(p&7).
// Each XCD streams its 8 pairs one 1MB WhT slice at a time (fits 4MB L2) -> slice fetched once.
__global__ __launch_bounds__(128) void k_attn4(const unsigned short* __restrict__ WhT_a,
                                               const float* __restrict__ ff,
                                               const int* __restrict__ idx,
                                               const int* __restrict__ cnt,
                                               float* __restrict__ G_a) {
    int blk = blockIdx.x;
    int xcd = blk & 7;
    int s = blk >> 3;
    int g = s >> 10;
    int n = s & 1023;
    int p = (g << 3) | xcd;
    int hop = p >> 4;
    int b = p & 15;
    int row = (b << 10) | n;
    int t = threadIdx.x;                  // 128
    __shared__ int sidx[CAP];
    __shared__ float sat[Hz][CAP];
    __shared__ f16x2 sp01[CAP], sp23[CAP];
    __shared__ float red[8];
    int deg = cnt[row];
    const unsigned short* WhTb = WhT_a + ((size_t)hop * BNc + ((size_t)b << 10)) * 512;
    const float* ffh = ff + (size_t)hop * BNc * 8;
    if (deg > 0) {
        if (t < deg) {
            int m = idx[(size_t)row * CAP + t];
            sidx[t] = m;
            int mrow = (b << 10) | m;
            float4 f1r = *(const float4*)&ffh[(size_t)row * 8];
            float4 f2m = *(const float4*)&ffh[(size_t)mrow * 8 + 4];
            float e0v = f1r.x + f2m.x;
            float e1v = f1r.y + f2m.y;
            float e2v = f1r.z + f2m.z;
            float e3v = f1r.w + f2m.w;
            sat[0][t] = e0v >= 0.f ? e0v : 0.2f * e0v;
            sat[1][t] = e1v >= 0.f ? e1v : 0.2f * e1v;
            sat[2][t] = e2v >= 0.f ? e2v : 0.2f * e2v;
            sat[3][t] = e3v >= 0.f ? e3v : 0.2f * e3v;
        }
        __syncthreads();
        int h = t >> 5, j0 = t & 31;      // 32 threads per head
        float mx = -1e30f;
        for (int j = j0; j < deg; j += 32) mx = fmaxf(mx, sat[h][j]);
#pragma unroll
        for (int mm = 1; mm < 32; mm <<= 1) mx = fmaxf(mx, __shfl_xor(mx, mm));
        if (j0 == 0) red[h] = mx;
        __syncthreads();
        mx = red[h];
        float sum = 0.f;
        for (int j = j0; j < deg; j += 32) {
            float v = expf(sat[h][j] - mx);
            sat[h][j] = v;
            sum += v;
        }
#pragma unroll
        for (int mm = 1; mm < 32; mm <<= 1) sum += __shfl_xor(sum, mm);
        if (j0 == 0) red[4 + h] = 0.25f / sum;    // fold 1/Hz into the weights
        __syncthreads();
        if (t < deg) {                    // scale + pack to f16 pairs
            float s0 = sat[0][t] * red[4];
            float s1 = sat[1][t] * red[5];
            float s2 = sat[2][t] * red[6];
            float s3 = sat[3][t] * red[7];
            f16x2 p01, p23;
            p01[0] = (_Float16)s0; p01[1] = (_Float16)s1;
            p23[0] = (_Float16)s2; p23[1] = (_Float16)s3;
            sp01[t] = p01;
            sp23[t] = p23;
        }
        __syncthreads();
        float acc = 0.f;
        const unsigned short* wb = WhTb + t * 4;
#pragma unroll 4
        for (int j = 0; j < deg; j++) {
            int m = sidx[j];
            uint2 raw = *(const uint2*)(wb + (size_t)m * 512);
            f16x2 w01 = __builtin_bit_cast(f16x2, raw.x);
            f16x2 w23 = __builtin_bit_cast(f16x2, raw.y);
            FDOT2(w01, sp01[j], acc);
            FDOT2(w23, sp23[j], acc);
        }
        G_a[((size_t)hop * BNc + row) * Dz + t] = acc;
    } else {
        // all-masked row: softmax of constant -9e15 = uniform 1/N over ALL m (JAX semantics)
        float acc = 0.f;
        const unsigned short* wb = WhTb + t * 4;
        for (int m = 0; m < Nz; m++) {
            uint2 raw = *(const uint2*)(wb + (size_t)m * 512);
            f16x2 w01 = __builtin_bit_cast(f16x2, raw.x);
            f16x2 w23 = __builtin_bit_cast(f16x2, raw.y);
            acc += (float)w01[0] + (float)w01[1] + (float)w23[0] + (float)w23[1];
        }
        G_a[((size_t)hop * BNc + row) * Dz + t] = acc * (1.f / (Hz * Nz));
    }
}

// ---------------- logits: one wave per row, 4 rows per block ------------------------------
__global__ __launch_bounds__(256) void k_logits4(const float* __restrict__ G_a, int hopA,
                                                 const float* __restrict__ u,
                                                 float* __restrict__ logits) {
    int row = blockIdx.x * 4 + (threadIdx.x >> 6);
    int lane = threadIdx.x & 63;
    int b = row >> 10;
    const float* g = G_a + ((size_t)hopA * BNc + row) * Dz;
    const float* ub = u + b * Dz;
    float s = g[lane] * ub[lane] + g[lane + 64] * ub[lane + 64];
#pragma unroll
    for (int off = 32; off; off >>= 1) s += __shfl_down(s, off);
    if (lane == 0) logits[row] = s;
}

// ---------------- u update: 8 blocks per batch, redundant softmax stats -------------------
__global__ __launch_bounds__(256) void k_upd(const float* __restrict__ G_a, int hopC,
                                             const float* __restrict__ logits,
                                             float* __restrict__ u) {
    int b = blockIdx.x >> 3;
    int chunk = blockIdx.x & 7;
    int t = threadIdx.x;                  // 256
    __shared__ float sp[1024];
    __shared__ float red[10];
    __shared__ float part[2][128];
    const float* l = logits + (size_t)b * Nz;
    float4 lv = *((const float4*)l + t);
    float mx = fmaxf(fmaxf(lv.x, lv.y), fmaxf(lv.z, lv.w));
#pragma unroll
    for (int mm = 1; mm < 64; mm <<= 1) mx = fmaxf(mx, __shfl_xor(mx, mm));
    if ((t & 63) == 0) red[t >> 6] = mx;
    __syncthreads();
    if (t == 0) {
        float m = red[0];
        for (int i = 1; i < 4; i++) m = fmaxf(m, red[i]);
        red[8] = m;
    }
    __syncthreads();
    mx = red[8];
    float e0 = expf(lv.x - mx), e1 = expf(lv.y - mx), e2 = expf(lv.z - mx), e3 = expf(lv.w - mx);
    float sum = e0 + e1 + e2 + e3;
#pragma unroll
    for (int mm = 1; mm < 64; mm <<= 1) sum += __shfl_xor(sum, mm);
    if ((t & 63) == 0) red[4 + (t >> 6)] = sum;
    __syncthreads();
    if (t == 0) {
        float ss = 0.f;
        for (int i = 0; i < 4; i++) ss += red[4 + i];
        red[9] = 1.f / ss;
    }
    __syncthreads();
    float inv = red[9];
    sp[t * 4] = e0 * inv;
    sp[t * 4 + 1] = e1 * inv;
    sp[t * 4 + 2] = e2 * inv;
    sp[t * 4 + 3] = e3 * inv;
    __syncthreads();
    int d = t & 127, half = t >> 7;
    const float* gc = G_a + ((size_t)hopC * BNc + (b << 10) + chunk * 128 + half * 64) * Dz + d;
    const float* pc = &sp[chunk * 128 + half * 64];
    float acc = 0.f;
#pragma unroll 4
    for (int j = 0; j < 64; j++) acc += gc[(size_t)j * Dz] * pc[j];
    part[half][d] = acc;
    __syncthreads();
    if (t < 128) atomicAdd(&u[b * Dz + t], part[0][t] + part[1][t]);
}

// ---------------- final out: sigmoid(logits), u, logits -----------------------------------
__global__ void k_fin(const float* __restrict__ logits, const float* __restrict__ u,
                      float* __restrict__ out) {
    int i = blockIdx.x * 256 + threadIdx.x;
    if (i < Bz * Nz) {
        float l = logits[i];
        out[i] = 1.f / (1.f + expf(-l));
        out[Bz * Nz + Bz * Dz + i] = l;
    }
    if (i < Bz * Dz) out[Bz * Nz + i] = u[i];
}

// ---------------- host ---------------------------------------------------------------------
extern "C" void kernel_launch(void* const* d_in, const int* in_sizes, int n_in,
                              void* d_out, int out_size, void* d_ws, size_t ws_size,
                              hipStream_t stream) {
    const int*   story    = (const int*)d_in[0];
    const int*   kb_len   = (const int*)d_in[1];
    const int*   conv_len = (const int*)d_in[2];
    const float* hidden   = (const float*)d_in[3];
    const float* dh       = (const float*)d_in[4];
    const float* adj      = (const float*)d_in[5];
    const float* emb      = (const float*)d_in[6];
    const float* gat_W    = (const float*)d_in[7];
    const float* gat_a    = (const float*)d_in[8];
    float* out = (float*)d_out;

    char* w = (char*)d_ws;
    auto alloc = [&](size_t bytes) {
        char* pp = w;
        w += (bytes + 255) & ~(size_t)255;
        return pp;
    };
    const size_t BN = (size_t)Bz * Nz;
    int*            idx  = (int*)           alloc(BN * CAP * 4);          // 8.4 MB
    int*            cnt  = (int*)           alloc(BN * 4);
    unsigned short* xhi  = (unsigned short*)alloc(4 * BN * Dz * 2);       // 16.8 MB
    unsigned short* xlo  = (unsigned short*)alloc(4 * BN * Dz * 2);
    unsigned short* wthi = (unsigned short*)alloc(4 * NC * 128 * 2);      // 0.6 MB
    unsigned short* wtlo = (unsigned short*)alloc(4 * NC * 128 * 2);
    unsigned short* WhT  = (unsigned short*)alloc(4 * BN * 512 * 2);      // 67 MB
    float*          ff   = (float*)         alloc(4 * BN * 8 * 4);        // 2.1 MB
    float*          G    = (float*)         alloc(4 * BN * Dz * 4);       // 33.6 MB
    float*          logits = (float*)       alloc(BN * 4);
    float*          u    = (float*)         alloc((size_t)Bz * Dz * 4);

    k_prep<<<BNc + 1152 + 8, 256, 0, stream>>>(adj, kb_len, conv_len, gat_W, gat_a, hidden,
                                               idx, cnt, wthi, wtlo, u);
    k_embed4<<<BNc, 128, 0, stream>>>(story, emb, dh, kb_len, conv_len, xhi, xlo);
    k_whf4<<<4608, 256, 0, stream>>>(xhi, xlo, wthi, wtlo, WhT, ff);
    k_attn4<<<4 * BNc, 128, 0, stream>>>(WhT, ff, idx, cnt, G);
    for (int hop = 0; hop < 3; hop++) {
        k_logits4<<<BNc / 4, 256, 0, stream>>>(G, hop, u, logits);
        k_upd<<<Bz * 8, 256, 0, stream>>>(G, hop + 1, logits, u);
    }
    k_fin<<<(Bz * Nz + 255) / 256, 256, 0, stream>>>(logits, u, out);
}

// Round 8
// 354.457 us; speedup vs baseline: 1.9776x; 1.0353x over previous
//
#include <hip/hip_runtime.h>
#include <hip/hip_bf16.h>
#include <math.h>

#define Bz 16
#define Nz 1024
#define Mz 4
#define Dz 128
#define Hz 4
#define VOCABz 32000
#define CAP 128
#define BNc (Bz * Nz)
#define NC 576            // 512 Wh cols (e*4+h) + 8 f-cols + 56 pad

typedef __attribute__((ext_vector_type(8))) short bf16x8;
typedef __attribute__((ext_vector_type(4))) float f32x4;
typedef __attribute__((ext_vector_type(2))) _Float16 f16x2;

#if defined(__has_builtin)
#if __has_builtin(__builtin_amdgcn_fdot2)
#define FDOT2(w, s, acc) acc = __builtin_amdgcn_fdot2((w), (s), (acc), false)
#endif
#endif
#ifndef FDOT2
#define FDOT2(w, s, acc) acc += (float)(w)[0] * (float)(s)[0] + (float)(w)[1] * (float)(s)[1]
#endif

__device__ inline unsigned short rne_bf16(float x) {
    unsigned u = __float_as_uint(x);
    unsigned r = (u + 0x7FFFu + ((u >> 16) & 1u)) >> 16;
    return (unsigned short)r;
}
__device__ inline float bf16_to_f(unsigned short h) {
    return __uint_as_float(((unsigned)h) << 16);
}
__device__ inline unsigned short f32_to_f16_bits(float x) {
    _Float16 hv = (_Float16)x;
    return __builtin_bit_cast(unsigned short, hv);
}
__device__ inline unsigned pack_f16(float a, float b) {
    f16x2 p;
    p[0] = (_Float16)a;
    p[1] = (_Float16)b;
    return __builtin_bit_cast(unsigned, p);
}

// ---------------- prep: CSR (blocks <BNc) + Wcat split (1152 blocks) + uinit --------------
__global__ __launch_bounds__(256) void k_prep(const float* __restrict__ adj,
                                              const int* __restrict__ kb_len,
                                              const int* __restrict__ conv_len,
                                              const float* __restrict__ gat_W,
                                              const float* __restrict__ gat_a,
                                              const float* __restrict__ hidden,
                                              int* __restrict__ idx, int* __restrict__ cnt,
                                              unsigned short* __restrict__ wthi,
                                              unsigned short* __restrict__ wtlo,
                                              float* __restrict__ u) {
    int blk = blockIdx.x;
    int t = threadIdx.x;
    if (blk < BNc) {                      // CSR row
        int row = blk;
        int b = row >> 10, n = row & 1023;
        __shared__ int scnt;
        if (t == 0) scnt = 0;
        __syncthreads();
        int ctx = kb_len[b] + conv_len[b];
        const float4 av = *((const float4*)(adj + (size_t)row * Nz) + t);
        int m0 = t * 4;
#pragma unroll
        for (int k = 0; k < 4; k++) {
            float a = k == 0 ? av.x : k == 1 ? av.y : k == 2 ? av.z : av.w;
            int m = m0 + k;
            bool on = (a > 0.f) || (m == n && n >= ctx);
            if (on) {
                int p = atomicAdd(&scnt, 1);
                if (p < CAP) idx[(size_t)row * CAP + p] = m;
            }
        }
        __syncthreads();
        if (t == 0) cnt[row] = scnt < CAP ? scnt : CAP;
    } else if (blk < BNc + 1152) {        // Wcat split: 4*576*128 elems
        int i = (blk - BNc) * 256 + t;
        int d = i & 127;
        int rest = i >> 7;                // hop*576 + c
        int c = rest % NC;
        int hop = rest / NC;
        float v;
        if (c < 512) {
            int h = c & 3, e = c >> 2;
            v = gat_W[(((size_t)(hop * 4 + h)) * 128 + d) * 128 + e];
        } else if (c < 520) {
            int q = c - 512;
            int h = q & 3, which = q >> 2;
            const float* wrow = gat_W + (((size_t)(hop * 4 + h)) * 128 + d) * 128;
            const float* arow = gat_a + ((size_t)(hop * 4 + h)) * 256 + which * 128;
            float s = 0.f;
            for (int e = 0; e < 128; e++) s += wrow[e] * arow[e];
            v = s;
        } else {
            v = 0.f;
        }
        unsigned short h = rne_bf16(v);
        wthi[i] = h;
        wtlo[i] = rne_bf16(v - bf16_to_f(h));
    } else {                              // u init
        int i = (blk - BNc - 1152) * 256 + t;
        if (i < Bz * Dz) u[i] = hidden[i];
    }
}

// ---------------- embed all 4 hops: x = sum emb rows (+ dh), split to bf16 hi/lo ----------
__global__ __launch_bounds__(128) void k_embed4(const int* __restrict__ story,
                                                const float* __restrict__ emb,
                                                const float* __restrict__ dh,
                                                const int* __restrict__ kb_len,
                                                const int* __restrict__ conv_len,
                                                unsigned short* __restrict__ xhi,
                                                unsigned short* __restrict__ xlo) {
    int row = blockIdx.x;                 // b*N + n
    int b = row >> 10, n = row & 1023;
    int d = threadIdx.x;                  // 128
    const int* st = story + (size_t)row * Mz;
    int s0 = st[0], s1 = st[1], s2 = st[2], s3 = st[3];
    int rel = n - (kb_len[b] - 1);
    float dhv = (rel >= 0 && rel < conv_len[b]) ? dh[((size_t)(b << 10) + rel) * Dz + d] : 0.f;
#pragma unroll
    for (int hop = 0; hop < 4; hop++) {
        const float* ek = emb + (size_t)hop * VOCABz * Dz;
        float acc = ek[(size_t)s0 * Dz + d] + ek[(size_t)s1 * Dz + d]
                  + ek[(size_t)s2 * Dz + d] + ek[(size_t)s3 * Dz + d] + dhv;
        unsigned short hb = rne_bf16(acc);
        size_t o = (size_t)hop * BNc * Dz + (size_t)row * Dz + d;
        xhi[o] = hb;
        xlo[o] = rne_bf16(acc - bf16_to_f(hb));
    }
}

// ---------------- GEMM X@Wcat (bf16x3 MFMA): WhT f16 [hop][row][c], ff fp32 [hop][row][8] --
#define AST 72
__global__ __launch_bounds__(256) void k_whf4(const unsigned short* __restrict__ xhi_a,
                                              const unsigned short* __restrict__ xlo_a,
                                              const unsigned short* __restrict__ wthi_a,
                                              const unsigned short* __restrict__ wtlo_a,
                                              unsigned short* __restrict__ WhT_a,
                                              float* __restrict__ ff) {
    int blk = blockIdx.x;
    int xcd = blk & 7;
    int s = blk >> 3;
    int hop = s / 144;
    int r = s - hop * 144;
    int rt = r / 9;
    int ct = r - rt * 9;
    int row0 = (xcd * 16 + rt) * 128;
    int t = threadIdx.x;
    int wave = t >> 6, lane = t & 63;
    int quad = lane >> 4, l16 = lane & 15;

    const unsigned short* xhi = xhi_a + (size_t)hop * BNc * Dz;
    const unsigned short* xlo = xlo_a + (size_t)hop * BNc * Dz;
    const unsigned short* wthi = wthi_a + (size_t)hop * NC * 128;
    const unsigned short* wtlo = wtlo_a + (size_t)hop * NC * 128;

    __shared__ unsigned short Ah[128 * AST], Al[128 * AST];   // X tile hi/lo [r][k]
    __shared__ unsigned short Bh[64 * AST], Bl[64 * AST];     // Wcat tile hi/lo [c][d]

    f32x4 acc[2][4];
#pragma unroll
    for (int mt = 0; mt < 2; mt++)
#pragma unroll
        for (int nt = 0; nt < 4; nt++) acc[mt][nt] = (f32x4)0.f;

    for (int ph = 0; ph < 2; ph++) {
        int kb = ph * 64;
        for (int i = t; i < 1024; i += 256) {
            int rr = i >> 3, c = (i & 7) * 8;
            *(uint4*)&Ah[rr * AST + c] = *(const uint4*)&xhi[(size_t)(row0 + rr) * Dz + kb + c];
            *(uint4*)&Al[rr * AST + c] = *(const uint4*)&xlo[(size_t)(row0 + rr) * Dz + kb + c];
        }
        for (int i = t; i < 512; i += 256) {
            int cr = i >> 3, cc = (i & 7) * 8;
            size_t src = ((size_t)(ct * 64 + cr)) * 128 + kb + cc;
            *(uint4*)&Bh[cr * AST + cc] = *(const uint4*)&wthi[src];
            *(uint4*)&Bl[cr * AST + cc] = *(const uint4*)&wtlo[src];
        }
        __syncthreads();
#pragma unroll
        for (int ks = 0; ks < 2; ks++) {
            int ko = ks * 32 + quad * 8;
            bf16x8 ah[2], al[2];
#pragma unroll
            for (int mt = 0; mt < 2; mt++) {
                int rr = wave * 32 + mt * 16 + l16;
                ah[mt] = *(const bf16x8*)&Ah[rr * AST + ko];
                al[mt] = *(const bf16x8*)&Al[rr * AST + ko];
            }
#pragma unroll
            for (int nt = 0; nt < 4; nt++) {
                int cc = nt * 16 + l16;
                bf16x8 bh = *(const bf16x8*)&Bh[cc * AST + ko];
                bf16x8 bl = *(const bf16x8*)&Bl[cc * AST + ko];
#pragma unroll
                for (int mt = 0; mt < 2; mt++) {
                    acc[mt][nt] = __builtin_amdgcn_mfma_f32_16x16x32_bf16(ah[mt], bh, acc[mt][nt], 0, 0, 0);
                    acc[mt][nt] = __builtin_amdgcn_mfma_f32_16x16x32_bf16(ah[mt], bl, acc[mt][nt], 0, 0, 0);
                    acc[mt][nt] = __builtin_amdgcn_mfma_f32_16x16x32_bf16(al[mt], bh, acc[mt][nt], 0, 0, 0);
                }
            }
        }
        __syncthreads();
    }

    if (ct < 8) {
        // repack 128x64 f16 tile through LDS (alias Ah), then coalesced uint4 stores
        unsigned short* St = Ah;          // stride AST=72, 128*72 shorts fits Ah
#pragma unroll
        for (int mt = 0; mt < 2; mt++)
#pragma unroll
            for (int nt = 0; nt < 4; nt++)
#pragma unroll
                for (int reg = 0; reg < 4; reg++) {
                    int rr = wave * 32 + mt * 16 + quad * 4 + reg;
                    int cc = nt * 16 + l16;
                    St[rr * AST + cc] = f32_to_f16_bits(acc[mt][nt][reg]);
                }
        __syncthreads();
        int rr = t >> 1, seg = t & 1;
        size_t gbase = ((size_t)hop * BNc + row0 + rr) * 512 + ct * 64 + seg * 32;
#pragma unroll
        for (int k = 0; k < 4; k++) {
            uint4 vv = *(uint4*)&St[rr * AST + seg * 32 + k * 8];
            *(uint4*)&WhT_a[gbase + k * 8] = vv;
        }
    } else {
        // f-columns: c = 512+q, q<8 -> ff[hop][row][q]  (only nt==0, l16<8 lanes)
        if (l16 < 8) {
#pragma unroll
            for (int mt = 0; mt < 2; mt++)
#pragma unroll
                for (int reg = 0; reg < 4; reg++) {
                    int row = row0 + wave * 32 + mt * 16 + quad * 4 + reg;
                    ff[((size_t)hop * BNc + row) * 8 + l16] = acc[mt][0][reg];
                }
        }
    }
}

// ---------------- sparse GAT attention: one wave per (row,hop), barrier-free --------------
// pair-per-XCD swizzle: pair p owned by XCD p&7; block = 4 waves = 4 consecutive n of pair.
// All softmax state in registers; per-j broadcast via readlane (no LDS, no __syncthreads).
__global__ __launch_bounds__(256) void k_attn4(const unsigned short* __restrict__ WhT_a,
                                               const float* __restrict__ ff,
                                               const int* __restrict__ idx,
                                               const int* __restrict__ cnt,
                                               float* __restrict__ G_a) {
    int blk = blockIdx.x;                 // 16384 blocks
    int xcd = blk & 7;
    int s = blk >> 3;                     // 0..2047
    int g = s >> 8;                       // 0..7
    int p = (g << 3) | xcd;               // pair 0..63
    int hop = p >> 4, b = p & 15;
    int wid = threadIdx.x >> 6, lane = threadIdx.x & 63;
    int n = ((s & 255) << 2) | wid;
    int row = (b << 10) | n;
    int deg = cnt[row];
    const unsigned short* WhTb = WhT_a + ((size_t)hop * BNc + ((size_t)b << 10)) * 512;
    const char* wblc = (const char*)WhTb + lane * 16;   // this lane's 8 cols
    const float* ffh = ff + (size_t)hop * BNc * 8;
    float accx = 0.f, accy = 0.f;
    if (deg > 0) {
        int m0 = lane < deg ? idx[(size_t)row * CAP + lane] : -1;
        int m1 = lane + 64 < deg ? idx[(size_t)row * CAP + lane + 64] : -1;
        float4 f1r = *(const float4*)&ffh[(size_t)row * 8];
        int m0c = m0 < 0 ? 0 : m0, m1c = m1 < 0 ? 0 : m1;
        float4 f2a = *(const float4*)&ffh[((size_t)(b << 10) + m0c) * 8 + 4];
        float4 f2b = *(const float4*)&ffh[((size_t)(b << 10) + m1c) * 8 + 4];
        float e0[4], e1[4];
        e0[0] = f1r.x + f2a.x; e0[1] = f1r.y + f2a.y; e0[2] = f1r.z + f2a.z; e0[3] = f1r.w + f2a.w;
        e1[0] = f1r.x + f2b.x; e1[1] = f1r.y + f2b.y; e1[2] = f1r.z + f2b.z; e1[3] = f1r.w + f2b.w;
#pragma unroll
        for (int h = 0; h < 4; h++) {
            e0[h] = e0[h] >= 0.f ? e0[h] : 0.2f * e0[h];
            e1[h] = e1[h] >= 0.f ? e1[h] : 0.2f * e1[h];
            if (m0 < 0) e0[h] = -1e30f;
            if (m1 < 0) e1[h] = -1e30f;
        }
        float mx[4], sum[4];
#pragma unroll
        for (int h = 0; h < 4; h++) {
            float m = fmaxf(e0[h], e1[h]);
#pragma unroll
            for (int mm = 1; mm < 64; mm <<= 1) m = fmaxf(m, __shfl_xor(m, mm));
            mx[h] = m;
        }
        float w0[4], w1[4];
#pragma unroll
        for (int h = 0; h < 4; h++) {
            w0[h] = expf(e0[h] - mx[h]);   // underflows to 0 for invalid slots
            w1[h] = expf(e1[h] - mx[h]);
            float sm = w0[h] + w1[h];
#pragma unroll
            for (int mm = 1; mm < 64; mm <<= 1) sm += __shfl_xor(sm, mm);
            sum[h] = sm;
        }
#pragma unroll
        for (int h = 0; h < 4; h++) {
            float inv = 0.25f / sum[h];    // fold 1/Hz
            w0[h] *= inv;
            w1[h] *= inv;
        }
        unsigned w01_0 = pack_f16(w0[0], w0[1]), w23_0 = pack_f16(w0[2], w0[3]);
        unsigned w01_1 = pack_f16(w1[0], w1[1]), w23_1 = pack_f16(w1[2], w1[3]);
        int moff0 = m0c << 10;             // byte offset: m * 512 cols * 2B
        int moff1 = m1c << 10;
        int dlo = deg < 64 ? deg : 64;
#pragma unroll 2
        for (int j = 0; j < dlo; j++) {
            int so = __builtin_amdgcn_readlane(moff0, j);
            unsigned a01 = (unsigned)__builtin_amdgcn_readlane((int)w01_0, j);
            unsigned a23 = (unsigned)__builtin_amdgcn_readlane((int)w23_0, j);
            uint4 raw = *(const uint4*)(wblc + so);
            f16x2 p01 = __builtin_bit_cast(f16x2, a01);
            f16x2 p23 = __builtin_bit_cast(f16x2, a23);
            FDOT2(__builtin_bit_cast(f16x2, raw.x), p01, accx);
            FDOT2(__builtin_bit_cast(f16x2, raw.y), p23, accx);
            FDOT2(__builtin_bit_cast(f16x2, raw.z), p01, accy);
            FDOT2(__builtin_bit_cast(f16x2, raw.w), p23, accy);
        }
        if (deg > 64) {
            for (int j = 0; j < deg - 64; j++) {
                int so = __builtin_amdgcn_readlane(moff1, j);
                unsigned a01 = (unsigned)__builtin_amdgcn_readlane((int)w01_1, j);
                unsigned a23 = (unsigned)__builtin_amdgcn_readlane((int)w23_1, j);
                uint4 raw = *(const uint4*)(wblc + so);
                f16x2 p01 = __builtin_bit_cast(f16x2, a01);
                f16x2 p23 = __builtin_bit_cast(f16x2, a23);
                FDOT2(__builtin_bit_cast(f16x2, raw.x), p01, accx);
                FDOT2(__builtin_bit_cast(f16x2, raw.y), p23, accx);
                FDOT2(__builtin_bit_cast(f16x2, raw.z), p01, accy);
                FDOT2(__builtin_bit_cast(f16x2, raw.w), p23, accy);
            }
        }
    } else {
        // all-masked row: softmax of constant -9e15 = uniform 1/N over ALL m (JAX semantics)
        for (int m = 0; m < Nz; m++) {
            uint4 raw = *(const uint4*)(wblc + (m << 10));
            f16x2 a = __builtin_bit_cast(f16x2, raw.x), c = __builtin_bit_cast(f16x2, raw.y);
            f16x2 d = __builtin_bit_cast(f16x2, raw.z), e = __builtin_bit_cast(f16x2, raw.w);
            accx += (float)a[0] + (float)a[1] + (float)c[0] + (float)c[1];
            accy += (float)d[0] + (float)d[1] + (float)e[0] + (float)e[1];
        }
        accx *= 1.f / (Hz * Nz);
        accy *= 1.f / (Hz * Nz);
    }
    float2 o = make_float2(accx, accy);
    *(float2*)&G_a[((size_t)hop * BNc + row) * Dz + lane * 2] = o;
}

// ---------------- logits: one wave per row, 4 rows per block ------------------------------
__global__ __launch_bounds__(256) void k_logits4(const float* __restrict__ G_a, int hopA,
                                                 const float* __restrict__ u,
                                                 float* __restrict__ logits) {
    int row = blockIdx.x * 4 + (threadIdx.x >> 6);
    int lane = threadIdx.x & 63;
    int b = row >> 10;
    const float* g = G_a + ((size_t)hopA * BNc + row) * Dz;
    const float* ub = u + b * Dz;
    float s = g[lane] * ub[lane] + g[lane + 64] * ub[lane + 64];
#pragma unroll
    for (int off = 32; off; off >>= 1) s += __shfl_down(s, off);
    if (lane == 0) logits[row] = s;
}

// ---------------- u update: 8 blocks per batch, redundant softmax stats -------------------
__global__ __launch_bounds__(256) void k_upd(const float* __restrict__ G_a, int hopC,
                                             const float* __restrict__ logits,
                                             float* __restrict__ u) {
    int b = blockIdx.x >> 3;
    int chunk = blockIdx.x & 7;
    int t = threadIdx.x;                  // 256
    __shared__ float sp[1024];
    __shared__ float red[10];
    __shared__ float part[2][128];
    const float* l = logits + (size_t)b * Nz;
    float4 lv = *((const float4*)l + t);
    float mx = fmaxf(fmaxf(lv.x, lv.y), fmaxf(lv.z, lv.w));
#pragma unroll
    for (int mm = 1; mm < 64; mm <<= 1) mx = fmaxf(mx, __shfl_xor(mx, mm));
    if ((t & 63) == 0) red[t >> 6] = mx;
    __syncthreads();
    if (t == 0) {
        float m = red[0];
        for (int i = 1; i < 4; i++) m = fmaxf(m, red[i]);
        red[8] = m;
    }
    __syncthreads();
    mx = red[8];
    float e0 = expf(lv.x - mx), e1 = expf(lv.y - mx), e2 = expf(lv.z - mx), e3 = expf(lv.w - mx);
    float sum = e0 + e1 + e2 + e3;
#pragma unroll
    for (int mm = 1; mm < 64; mm <<= 1) sum += __shfl_xor(sum, mm);
    if ((t & 63) == 0) red[4 + (t >> 6)] = sum;
    __syncthreads();
    if (t == 0) {
        float ss = 0.f;
        for (int i = 0; i < 4; i++) ss += red[4 + i];
        red[9] = 1.f / ss;
    }
    __syncthreads();
    float inv = red[9];
    sp[t * 4] = e0 * inv;
    sp[t * 4 + 1] = e1 * inv;
    sp[t * 4 + 2] = e2 * inv;
    sp[t * 4 + 3] = e3 * inv;
    __syncthreads();
    int d = t & 127, half = t >> 7;
    const float* gc = G_a + ((size_t)hopC * BNc + (b << 10) + chunk * 128 + half * 64) * Dz + d;
    const float* pc = &sp[chunk * 128 + half * 64];
    float acc = 0.f;
#pragma unroll 4
    for (int j = 0; j < 64; j++) acc += gc[(size_t)j * Dz] * pc[j];
    part[half][d] = acc;
    __syncthreads();
    if (t < 128) atomicAdd(&u[b * Dz + t], part[0][t] + part[1][t]);
}

// ---------------- final out: sigmoid(logits), u, logits -----------------------------------
__global__ void k_fin(const float* __restrict__ logits, const float* __restrict__ u,
                      float* __restrict__ out) {
    int i = blockIdx.x * 256 + threadIdx.x;
    if (i < Bz * Nz) {
        float l = logits[i];
        out[i] = 1.f / (1.f + expf(-l));
        out[Bz * Nz + Bz * Dz + i] = l;
    }
    if (i < Bz * Dz) out[Bz * Nz + i] = u[i];
}

// ---------------- host ---------------------------------------------------------------------
extern "C" void kernel_launch(void* const* d_in, const int* in_sizes, int n_in,
                              void* d_out, int out_size, void* d_ws, size_t ws_size,
                              hipStream_t stream) {
    const int*   story    = (const int*)d_in[0];
    const int*   kb_len   = (const int*)d_in[1];
    const int*   conv_len = (const int*)d_in[2];
    const float* hidden   = (const float*)d_in[3];
    const float* dh       = (const float*)d_in[4];
    const float* adj      = (const float*)d_in[5];
    const float* emb      = (const float*)d_in[6];
    const float* gat_W    = (const float*)d_in[7];
    const float* gat_a    = (const float*)d_in[8];
    float* out = (float*)d_out;

    char* w = (char*)d_ws;
    auto alloc = [&](size_t bytes) {
        char* pp = w;
        w += (bytes + 255) & ~(size_t)255;
        return pp;
    };
    const size_t BN = (size_t)Bz * Nz;
    int*            idx  = (int*)           alloc(BN * CAP * 4);          // 8.4 MB
    int*            cnt  = (int*)           alloc(BN * 4);
    unsigned short* xhi  = (unsigned short*)alloc(4 * BN * Dz * 2);       // 16.8 MB
    unsigned short* xlo  = (unsigned short*)alloc(4 * BN * Dz * 2);
    unsigned short* wthi = (unsigned short*)alloc(4 * NC * 128 * 2);      // 0.6 MB
    unsigned short* wtlo = (unsigned short*)alloc(4 * NC * 128 * 2);
    unsigned short* WhT  = (unsigned short*)alloc(4 * BN * 512 * 2);      // 67 MB
    float*          ff   = (float*)         alloc(4 * BN * 8 * 4);        // 2.1 MB
    float*          G    = (float*)         alloc(4 * BN * Dz * 4);       // 33.6 MB
    float*          logits = (float*)       alloc(BN * 4);
    float*          u    = (float*)         alloc((size_t)Bz * Dz * 4);

    k_prep<<<BNc + 1152 + 8, 256, 0, stream>>>(adj, kb_len, conv_len, gat_W, gat_a, hidden,
                                               idx, cnt, wthi, wtlo, u);
    k_embed4<<<BNc, 128, 0, stream>>>(story, emb, dh, kb_len, conv_len, xhi, xlo);
    k_whf4<<<4608, 256, 0, stream>>>(xhi, xlo, wthi, wtlo, WhT, ff);
    k_attn4<<<16384, 256, 0, stream>>>(WhT, ff, idx, cnt, G);
    for (int hop = 0; hop < 3; hop++) {
        k_logits4<<<BNc / 4, 256, 0, stream>>>(G, hop, u, logits);
        k_upd<<<Bz * 8, 256, 0, stream>>>(G, hop + 1, logits, u);
    }
    k_fin<<<(Bz * Nz + 255) / 256, 256, 0, stream>>>(logits, u, out);
}

// Round 9
// 329.439 us; speedup vs baseline: 2.1278x; 1.0759x over previous
//
#include <hip/hip_runtime.h>
#include <hip/hip_bf16.h>
#include <math.h>

#define Bz 16
#define Nz 1024
#define Mz 4
#define Dz 128
#define Hz 4
#define VOCABz 32000
#define CAP 128
#define BNc (Bz * Nz)
#define NC 576            // 512 Wh cols (e*4+h) + 8 f-cols + 56 pad

typedef __attribute__((ext_vector_type(8))) short s16x8;
typedef __attribute__((ext_vector_type(8))) _Float16 f16x8;
typedef __attribute__((ext_vector_type(4))) float f32x4;
typedef __attribute__((ext_vector_type(2))) _Float16 f16x2;

#if defined(__has_builtin)
#if __has_builtin(__builtin_amdgcn_fdot2)
#define FDOT2(w, s, acc) acc = __builtin_amdgcn_fdot2((w), (s), (acc), false)
#endif
#endif
#ifndef FDOT2
#define FDOT2(w, s, acc) acc += (float)(w)[0] * (float)(s)[0] + (float)(w)[1] * (float)(s)[1]
#endif
#define BC16(x) __builtin_bit_cast(f16x2, (x))

__device__ inline unsigned short f32_to_f16_bits(float x) {
    _Float16 hv = (_Float16)x;
    return __builtin_bit_cast(unsigned short, hv);
}
__device__ inline float f16_bits_to_f32(unsigned short h) {
    return (float)__builtin_bit_cast(_Float16, h);
}
__device__ inline unsigned pack_f16(float a, float b) {
    f16x2 p;
    p[0] = (_Float16)a;
    p[1] = (_Float16)b;
    return __builtin_bit_cast(unsigned, p);
}

// ---------------- prep: CSR (blocks <BNc) + Wcat f16 (1152 blocks) + uinit ----------------
// Wcat[hop][c][d]: c<512 -> W[hop][h=c&3][d][e=c>>2]; c in [512,520): q=c-512,
//   col = sum_e W[hop][h=q&3][d][e] * a[hop][h][(q>>2)*128+e]; c>=520 -> 0.
__global__ __launch_bounds__(256) void k_prep(const float* __restrict__ adj,
                                              const int* __restrict__ kb_len,
                                              const int* __restrict__ conv_len,
                                              const float* __restrict__ gat_W,
                                              const float* __restrict__ gat_a,
                                              const float* __restrict__ hidden,
                                              int* __restrict__ idx, int* __restrict__ cnt,
                                              unsigned short* __restrict__ wt,
                                              float* __restrict__ u) {
    int blk = blockIdx.x;
    int t = threadIdx.x;
    if (blk < BNc) {                      // CSR row
        int row = blk;
        int b = row >> 10, n = row & 1023;
        __shared__ int scnt;
        if (t == 0) scnt = 0;
        __syncthreads();
        int ctx = kb_len[b] + conv_len[b];
        const float4 av = *((const float4*)(adj + (size_t)row * Nz) + t);
        int m0 = t * 4;
#pragma unroll
        for (int k = 0; k < 4; k++) {
            float a = k == 0 ? av.x : k == 1 ? av.y : k == 2 ? av.z : av.w;
            int m = m0 + k;
            bool on = (a > 0.f) || (m == n && n >= ctx);
            if (on) {
                int p = atomicAdd(&scnt, 1);
                if (p < CAP) idx[(size_t)row * CAP + p] = m;
            }
        }
        __syncthreads();
        if (t == 0) cnt[row] = scnt < CAP ? scnt : CAP;
    } else if (blk < BNc + 1152) {        // Wcat: 4*576*128 elems
        int i = (blk - BNc) * 256 + t;
        int d = i & 127;
        int rest = i >> 7;                // hop*576 + c
        int c = rest % NC;
        int hop = rest / NC;
        float v;
        if (c < 512) {
            int h = c & 3, e = c >> 2;
            v = gat_W[(((size_t)(hop * 4 + h)) * 128 + d) * 128 + e];
        } else if (c < 520) {
            int q = c - 512;
            int h = q & 3, which = q >> 2;
            const float* wrow = gat_W + (((size_t)(hop * 4 + h)) * 128 + d) * 128;
            const float* arow = gat_a + ((size_t)(hop * 4 + h)) * 256 + which * 128;
            float s = 0.f;
            for (int e = 0; e < 128; e++) s += wrow[e] * arow[e];
            v = s;
        } else {
            v = 0.f;
        }
        wt[i] = f32_to_f16_bits(v);
    } else {                              // u init
        int i = (blk - BNc - 1152) * 256 + t;
        if (i < Bz * Dz) u[i] = hidden[i];
    }
}

// ---------------- embed all 4 hops: x = sum emb rows (+ dh), split to f16 hi/lo -----------
__global__ __launch_bounds__(128) void k_embed4(const int* __restrict__ story,
                                                const float* __restrict__ emb,
                                                const float* __restrict__ dh,
                                                const int* __restrict__ kb_len,
                                                const int* __restrict__ conv_len,
                                                unsigned short* __restrict__ xhi,
                                                unsigned short* __restrict__ xlo) {
    int row = blockIdx.x;                 // b*N + n
    int b = row >> 10, n = row & 1023;
    int d = threadIdx.x;                  // 128
    const int* st = story + (size_t)row * Mz;
    int s0 = st[0], s1 = st[1], s2 = st[2], s3 = st[3];
    int rel = n - (kb_len[b] - 1);
    float dhv = (rel >= 0 && rel < conv_len[b]) ? dh[((size_t)(b << 10) + rel) * Dz + d] : 0.f;
#pragma unroll
    for (int hop = 0; hop < 4; hop++) {
        const float* ek = emb + (size_t)hop * VOCABz * Dz;
        float acc = ek[(size_t)s0 * Dz + d] + ek[(size_t)s1 * Dz + d]
                  + ek[(size_t)s2 * Dz + d] + ek[(size_t)s3 * Dz + d] + dhv;
        unsigned short hb = f32_to_f16_bits(acc);
        size_t o = (size_t)hop * BNc * Dz + (size_t)row * Dz + d;
        xhi[o] = hb;
        xlo[o] = f32_to_f16_bits(acc - f16_bits_to_f32(hb));
    }
}

// ---------------- GEMM X@Wcat (f16 2-MFMA): WhT f16 [hop][row][c], ff fp32 [hop][row][8] --
#define AST 72
__global__ __launch_bounds__(256) void k_whf4(const unsigned short* __restrict__ xhi_a,
                                              const unsigned short* __restrict__ xlo_a,
                                              const unsigned short* __restrict__ wt_a,
                                              unsigned short* __restrict__ WhT_a,
                                              float* __restrict__ ff) {
    int blk = blockIdx.x;
    int xcd = blk & 7;
    int s = blk >> 3;
    int hop = s / 144;
    int r = s - hop * 144;
    int rt = r / 9;
    int ct = r - rt * 9;
    int row0 = (xcd * 16 + rt) * 128;
    int t = threadIdx.x;
    int wave = t >> 6, lane = t & 63;
    int quad = lane >> 4, l16 = lane & 15;

    const unsigned short* xhi = xhi_a + (size_t)hop * BNc * Dz;
    const unsigned short* xlo = xlo_a + (size_t)hop * BNc * Dz;
    const unsigned short* wt = wt_a + (size_t)hop * NC * 128;

    __shared__ unsigned short Ah[128 * AST], Al[128 * AST];   // X tile hi/lo [r][k]
    __shared__ unsigned short Bh[64 * AST];                   // Wcat tile [c][d]

    f32x4 acc[2][4];
#pragma unroll
    for (int mt = 0; mt < 2; mt++)
#pragma unroll
        for (int nt = 0; nt < 4; nt++) acc[mt][nt] = (f32x4)0.f;

    for (int ph = 0; ph < 2; ph++) {
        int kb = ph * 64;
        for (int i = t; i < 1024; i += 256) {
            int rr = i >> 3, c = (i & 7) * 8;
            *(uint4*)&Ah[rr * AST + c] = *(const uint4*)&xhi[(size_t)(row0 + rr) * Dz + kb + c];
            *(uint4*)&Al[rr * AST + c] = *(const uint4*)&xlo[(size_t)(row0 + rr) * Dz + kb + c];
        }
        for (int i = t; i < 512; i += 256) {
            int cr = i >> 3, cc = (i & 7) * 8;
            *(uint4*)&Bh[cr * AST + cc] =
                *(const uint4*)&wt[((size_t)(ct * 64 + cr)) * 128 + kb + cc];
        }
        __syncthreads();
#pragma unroll
        for (int ks = 0; ks < 2; ks++) {
            int ko = ks * 32 + quad * 8;
            f16x8 ah[2], al[2];
#pragma unroll
            for (int mt = 0; mt < 2; mt++) {
                int rr = wave * 32 + mt * 16 + l16;
                ah[mt] = __builtin_bit_cast(f16x8, *(const s16x8*)&Ah[rr * AST + ko]);
                al[mt] = __builtin_bit_cast(f16x8, *(const s16x8*)&Al[rr * AST + ko]);
            }
#pragma unroll
            for (int nt = 0; nt < 4; nt++) {
                int cc = nt * 16 + l16;
                f16x8 bh = __builtin_bit_cast(f16x8, *(const s16x8*)&Bh[cc * AST + ko]);
#pragma unroll
                for (int mt = 0; mt < 2; mt++) {
                    acc[mt][nt] = __builtin_amdgcn_mfma_f32_16x16x32_f16(ah[mt], bh, acc[mt][nt], 0, 0, 0);
                    acc[mt][nt] = __builtin_amdgcn_mfma_f32_16x16x32_f16(al[mt], bh, acc[mt][nt], 0, 0, 0);
                }
            }
        }
        __syncthreads();
    }

    if (ct < 8) {
        // repack 128x64 f16 tile through LDS (alias Ah), then coalesced uint4 stores
        unsigned short* St = Ah;
#pragma unroll
        for (int mt = 0; mt < 2; mt++)
#pragma unroll
            for (int nt = 0; nt < 4; nt++)
#pragma unroll
                for (int reg = 0; reg < 4; reg++) {
                    int rr = wave * 32 + mt * 16 + quad * 4 + reg;
                    int cc = nt * 16 + l16;
                    St[rr * AST + cc] = f32_to_f16_bits(acc[mt][nt][reg]);
                }
        __syncthreads();
        int rr = t >> 1, seg = t & 1;
        size_t gbase = ((size_t)hop * BNc + row0 + rr) * 512 + ct * 64 + seg * 32;
#pragma unroll
        for (int k = 0; k < 4; k++) {
            uint4 vv = *(uint4*)&St[rr * AST + seg * 32 + k * 8];
            *(uint4*)&WhT_a[gbase + k * 8] = vv;
        }
    } else {
        if (l16 < 8) {
#pragma unroll
            for (int mt = 0; mt < 2; mt++)
#pragma unroll
                for (int reg = 0; reg < 4; reg++) {
                    int row = row0 + wave * 32 + mt * 16 + quad * 4 + reg;
                    ff[((size_t)hop * BNc + row) * 8 + l16] = acc[mt][0][reg];
                }
        }
    }
}

// ---------------- full-wave single-row attention (fallback: deg>32 or deg==0) -------------
__device__ void attn_row_full(const unsigned short* __restrict__ WhTb,
                              const float* __restrict__ ffh,
                              const int* __restrict__ idx, int deg, int b, int row,
                              int lane, float* __restrict__ Gp) {
    const char* wblc = (const char*)WhTb + lane * 16;
    float accx = 0.f, accy = 0.f;
    if (deg > 0) {
        int m0 = lane < deg ? idx[(size_t)row * CAP + lane] : -1;
        int m1 = lane + 64 < deg ? idx[(size_t)row * CAP + lane + 64] : -1;
        float4 f1r = *(const float4*)&ffh[(size_t)row * 8];
        int m0c = m0 < 0 ? 0 : m0, m1c = m1 < 0 ? 0 : m1;
        float4 f2a = *(const float4*)&ffh[((size_t)(b << 10) + m0c) * 8 + 4];
        float4 f2b = *(const float4*)&ffh[((size_t)(b << 10) + m1c) * 8 + 4];
        float e0[4], e1[4];
        e0[0] = f1r.x + f2a.x; e0[1] = f1r.y + f2a.y; e0[2] = f1r.z + f2a.z; e0[3] = f1r.w + f2a.w;
        e1[0] = f1r.x + f2b.x; e1[1] = f1r.y + f2b.y; e1[2] = f1r.z + f2b.z; e1[3] = f1r.w + f2b.w;
#pragma unroll
        for (int h = 0; h < 4; h++) {
            e0[h] = e0[h] >= 0.f ? e0[h] : 0.2f * e0[h];
            e1[h] = e1[h] >= 0.f ? e1[h] : 0.2f * e1[h];
            if (m0 < 0) e0[h] = -1e30f;
            if (m1 < 0) e1[h] = -1e30f;
        }
        float w0[4], w1[4];
#pragma unroll
        for (int h = 0; h < 4; h++) {
            float m = fmaxf(e0[h], e1[h]);
#pragma unroll
            for (int mm = 1; mm < 64; mm <<= 1) m = fmaxf(m, __shfl_xor(m, mm));
            w0[h] = expf(e0[h] - m);
            w1[h] = expf(e1[h] - m);
            float sm = w0[h] + w1[h];
#pragma unroll
            for (int mm = 1; mm < 64; mm <<= 1) sm += __shfl_xor(sm, mm);
            float inv = 0.25f / sm;
            w0[h] *= inv;
            w1[h] *= inv;
        }
        unsigned w01_0 = pack_f16(w0[0], w0[1]), w23_0 = pack_f16(w0[2], w0[3]);
        unsigned w01_1 = pack_f16(w1[0], w1[1]), w23_1 = pack_f16(w1[2], w1[3]);
        int moff0 = m0c << 10;
        int moff1 = m1c << 10;
        int dlo = deg < 64 ? deg : 64;
#pragma unroll 2
        for (int j = 0; j < dlo; j++) {
            int so = __builtin_amdgcn_readlane(moff0, j);
            unsigned a01 = (unsigned)__builtin_amdgcn_readlane((int)w01_0, j);
            unsigned a23 = (unsigned)__builtin_amdgcn_readlane((int)w23_0, j);
            uint4 raw = *(const uint4*)(wblc + so);
            f16x2 p01 = BC16(a01), p23 = BC16(a23);
            FDOT2(BC16(raw.x), p01, accx);
            FDOT2(BC16(raw.y), p23, accx);
            FDOT2(BC16(raw.z), p01, accy);
            FDOT2(BC16(raw.w), p23, accy);
        }
        for (int j = 0; j < deg - 64; j++) {
            int so = __builtin_amdgcn_readlane(moff1, j);
            unsigned a01 = (unsigned)__builtin_amdgcn_readlane((int)w01_1, j);
            unsigned a23 = (unsigned)__builtin_amdgcn_readlane((int)w23_1, j);
            uint4 raw = *(const uint4*)(wblc + so);
            f16x2 p01 = BC16(a01), p23 = BC16(a23);
            FDOT2(BC16(raw.x), p01, accx);
            FDOT2(BC16(raw.y), p23, accx);
            FDOT2(BC16(raw.z), p01, accy);
            FDOT2(BC16(raw.w), p23, accy);
        }
    } else {
        // all-masked row: softmax of constant -9e15 = uniform 1/N over ALL m (JAX semantics)
        for (int m = 0; m < Nz; m++) {
            uint4 raw = *(const uint4*)(wblc + (m << 10));
            accx += (float)BC16(raw.x)[0] + (float)BC16(raw.x)[1]
                  + (float)BC16(raw.y)[0] + (float)BC16(raw.y)[1];
            accy += (float)BC16(raw.z)[0] + (float)BC16(raw.z)[1]
                  + (float)BC16(raw.w)[0] + (float)BC16(raw.w)[1];
        }
        accx *= 1.f / (Hz * Nz);
        accy *= 1.f / (Hz * Nz);
    }
    *(float2*)&Gp[lane * 2] = make_float2(accx, accy);
}

// ---------------- sparse GAT attention: TWO rows per wave (32-lane halves) ----------------
// pair-per-XCD swizzle preserved. Fast path (both degs in [1,32]): softmax reductions are
// 5 shfl_xor rounds within each half; j-loop covers one neighbor of EACH row per iter via
// per-lane __shfl broadcasts. deg>32 or deg==0 -> full-wave fallback per row (~1% of waves).
__global__ __launch_bounds__(256) void k_attn4(const unsigned short* __restrict__ WhT_a,
                                               const float* __restrict__ ff,
                                               const int* __restrict__ idx,
                                               const int* __restrict__ cnt,
                                               float* __restrict__ G_a) {
    int blk = blockIdx.x;                 // 8192 blocks
    int xcd = blk & 7;
    int s = blk >> 3;                     // 0..1023
    int g = s >> 7;                       // 0..7
    int p = (g << 3) | xcd;               // pair 0..63
    int hop = p >> 4, b = p & 15;
    int wid = threadIdx.x >> 6, lane = threadIdx.x & 63;
    int r2 = ((s & 127) << 2) | wid;      // row-pair 0..511
    int half = lane >> 5, l32 = lane & 31;
    int n = (r2 << 1) | half;
    int row = (b << 10) | n;
    const unsigned short* WhTb = WhT_a + ((size_t)hop * BNc + ((size_t)b << 10)) * 512;
    const float* ffh = ff + (size_t)hop * BNc * 8;
    int deg = cnt[row];
    int deg0 = __shfl(deg, 0), deg1 = __shfl(deg, 32);
    if (deg0 > 0 && deg1 > 0 && deg0 <= 32 && deg1 <= 32) {
        int m = l32 < deg ? idx[(size_t)row * CAP + l32] : -1;
        int mc = m < 0 ? 0 : m;
        float4 f1r = *(const float4*)&ffh[(size_t)row * 8];
        float4 f2m = *(const float4*)&ffh[((size_t)(b << 10) + mc) * 8 + 4];
        float e[4];
        e[0] = f1r.x + f2m.x; e[1] = f1r.y + f2m.y; e[2] = f1r.z + f2m.z; e[3] = f1r.w + f2m.w;
        float w[4];
#pragma unroll
        for (int h = 0; h < 4; h++) {
            e[h] = e[h] >= 0.f ? e[h] : 0.2f * e[h];
            if (m < 0) e[h] = -1e30f;
        }
#pragma unroll
        for (int h = 0; h < 4; h++) {
            float mx = e[h];
#pragma unroll
            for (int mm = 1; mm < 32; mm <<= 1) mx = fmaxf(mx, __shfl_xor(mx, mm));
            w[h] = expf(e[h] - mx);
            float sm = w[h];
#pragma unroll
            for (int mm = 1; mm < 32; mm <<= 1) sm += __shfl_xor(sm, mm);
            w[h] *= 0.25f / sm;
        }
        int w01 = (int)pack_f16(w[0], w[1]);
        int w23 = (int)pack_f16(w[2], w[3]);
        int moff = mc << 10;
        int dmax = deg0 > deg1 ? deg0 : deg1;
        int srcbase = lane & 32;
        const char* wbl = (const char*)WhTb + l32 * 32;   // this lane's 16 cols
        float a0 = 0.f, a1 = 0.f, a2 = 0.f, a3 = 0.f;
#pragma unroll 2
        for (int j = 0; j < dmax; j++) {
            int src = srcbase + j;
            int vo = __shfl(moff, src);
            unsigned b01 = (unsigned)__shfl(w01, src);
            unsigned b23 = (unsigned)__shfl(w23, src);
            uint4 r0 = *(const uint4*)(wbl + vo);
            uint4 r1 = *(const uint4*)(wbl + vo + 16);
            f16x2 p01 = BC16(b01), p23 = BC16(b23);
            FDOT2(BC16(r0.x), p01, a0);
            FDOT2(BC16(r0.y), p23, a0);
            FDOT2(BC16(r0.z), p01, a1);
            FDOT2(BC16(r0.w), p23, a1);
            FDOT2(BC16(r1.x), p01, a2);
            FDOT2(BC16(r1.y), p23, a2);
            FDOT2(BC16(r1.z), p01, a3);
            FDOT2(BC16(r1.w), p23, a3);
        }
        *(float4*)&G_a[((size_t)hop * BNc + row) * Dz + l32 * 4] = make_float4(a0, a1, a2, a3);
    } else {
        int row0 = (b << 10) | (r2 << 1);
        attn_row_full(WhTb, ffh, idx, deg0, b, row0, lane,
                      &G_a[((size_t)hop * BNc + row0) * Dz]);
        attn_row_full(WhTb, ffh, idx, deg1, b, row0 + 1, lane,
                      &G_a[((size_t)hop * BNc + row0 + 1) * Dz]);
    }
}

// ---------------- logits: one wave per row, 4 rows per block ------------------------------
__global__ __launch_bounds__(256) void k_logits4(const float* __restrict__ G_a, int hopA,
                                                 const float* __restrict__ u,
                                                 float* __restrict__ logits) {
    int row = blockIdx.x * 4 + (threadIdx.x >> 6);
    int lane = threadIdx.x & 63;
    int b = row >> 10;
    const float* g = G_a + ((size_t)hopA * BNc + row) * Dz;
    const float* ub = u + b * Dz;
    float s = g[lane] * ub[lane] + g[lane + 64] * ub[lane + 64];
#pragma unroll
    for (int off = 32; off; off >>= 1) s += __shfl_down(s, off);
    if (lane == 0) logits[row] = s;
}

// ---------------- u update: 8 blocks per batch, redundant softmax stats -------------------
__global__ __launch_bounds__(256) void k_upd(const float* __restrict__ G_a, int hopC,
                                             const float* __restrict__ logits,
                                             float* __restrict__ u) {
    int b = blockIdx.x >> 3;
    int chunk = blockIdx.x & 7;
    int t = threadIdx.x;                  // 256
    __shared__ float sp[1024];
    __shared__ float red[10];
    __shared__ float part[2][128];
    const float* l = logits + (size_t)b * Nz;
    float4 lv = *((const float4*)l + t);
    float mx = fmaxf(fmaxf(lv.x, lv.y), fmaxf(lv.z, lv.w));
#pragma unroll
    for (int mm = 1; mm < 64; mm <<= 1) mx = fmaxf(mx, __shfl_xor(mx, mm));
    if ((t & 63) == 0) red[t >> 6] = mx;
    __syncthreads();
    if (t == 0) {
        float m = red[0];
        for (int i = 1; i < 4; i++) m = fmaxf(m, red[i]);
        red[8] = m;
    }
    __syncthreads();
    mx = red[8];
    float e0 = expf(lv.x - mx), e1 = expf(lv.y - mx), e2 = expf(lv.z - mx), e3 = expf(lv.w - mx);
    float sum = e0 + e1 + e2 + e3;
#pragma unroll
    for (int mm = 1; mm < 64; mm <<= 1) sum += __shfl_xor(sum, mm);
    if ((t & 63) == 0) red[4 + (t >> 6)] = sum;
    __syncthreads();
    if (t == 0) {
        float ss = 0.f;
        for (int i = 0; i < 4; i++) ss += red[4 + i];
        red[9] = 1.f / ss;
    }
    __syncthreads();
    float inv = red[9];
    sp[t * 4] = e0 * inv;
    sp[t * 4 + 1] = e1 * inv;
    sp[t * 4 + 2] = e2 * inv;
    sp[t * 4 + 3] = e3 * inv;
    __syncthreads();
    int d = t & 127, half = t >> 7;
    const float* gc = G_a + ((size_t)hopC * BNc + (b << 10) + chunk * 128 + half * 64) * Dz + d;
    const float* pc = &sp[chunk * 128 + half * 64];
    float acc = 0.f;
#pragma unroll 4
    for (int j = 0; j < 64; j++) acc += gc[(size_t)j * Dz] * pc[j];
    part[half][d] = acc;
    __syncthreads();
    if (t < 128) atomicAdd(&u[b * Dz + t], part[0][t] + part[1][t]);
}

// ---------------- final out: sigmoid(logits), u, logits -----------------------------------
__global__ void k_fin(const float* __restrict__ logits, const float* __restrict__ u,
                      float* __restrict__ out) {
    int i = blockIdx.x * 256 + threadIdx.x;
    if (i < Bz * Nz) {
        float l = logits[i];
        out[i] = 1.f / (1.f + expf(-l));
        out[Bz * Nz + Bz * Dz + i] = l;
    }
    if (i < Bz * Dz) out[Bz * Nz + i] = u[i];
}

// ---------------- host ---------------------------------------------------------------------
extern "C" void kernel_launch(void* const* d_in, const int* in_sizes, int n_in,
                              void* d_out, int out_size, void* d_ws, size_t ws_size,
                              hipStream_t stream) {
    const int*   story    = (const int*)d_in[0];
    const int*   kb_len   = (const int*)d_in[1];
    const int*   conv_len = (const int*)d_in[2];
    const float* hidden   = (const float*)d_in[3];
    const float* dh       = (const float*)d_in[4];
    const float* adj      = (const float*)d_in[5];
    const float* emb      = (const float*)d_in[6];
    const float* gat_W    = (const float*)d_in[7];
    const float* gat_a    = (const float*)d_in[8];
    float* out = (float*)d_out;

    char* w = (char*)d_ws;
    auto alloc = [&](size_t bytes) {
        char* pp = w;
        w += (bytes + 255) & ~(size_t)255;
        return pp;
    };
    const size_t BN = (size_t)Bz * Nz;
    int*            idx  = (int*)           alloc(BN * CAP * 4);          // 8.4 MB
    int*            cnt  = (int*)           alloc(BN * 4);
    unsigned short* xhi  = (unsigned short*)alloc(4 * BN * Dz * 2);       // 16.8 MB
    unsigned short* xlo  = (unsigned short*)alloc(4 * BN * Dz * 2);
    unsigned short* wt   = (unsigned short*)alloc(4 * NC * 128 * 2);      // 0.6 MB
    unsigned short* WhT  = (unsigned short*)alloc(4 * BN * 512 * 2);      // 67 MB
    float*          ff   = (float*)         alloc(4 * BN * 8 * 4);        // 2.1 MB
    float*          G    = (float*)         alloc(4 * BN * Dz * 4);       // 33.6 MB
    float*          logits = (float*)       alloc(BN * 4);
    float*          u    = (float*)         alloc((size_t)Bz * Dz * 4);

    k_prep<<<BNc + 1152 + 8, 256, 0, stream>>>(adj, kb_len, conv_len, gat_W, gat_a, hidden,
                                               idx, cnt, wt, u);
    k_embed4<<<BNc, 128, 0, stream>>>(story, emb, dh, kb_len, conv_len, xhi, xlo);
    k_whf4<<<4608, 256, 0, stream>>>(xhi, xlo, wt, WhT, ff);
    k_attn4<<<8192, 256, 0, stream>>>(WhT, ff, idx, cnt, G);
    for (int hop = 0; hop < 3; hop++) {
        k_logits4<<<BNc / 4, 256, 0, stream>>>(G, hop, u, logits);
        k_upd<<<Bz * 8, 256, 0, stream>>>(G, hop + 1, logits, u);
    }
    k_fin<<<(Bz * Nz + 255) / 256, 256, 0, stream>>>(logits, u, out);
}

// Round 10
// 317.925 us; speedup vs baseline: 2.2048x; 1.0362x over previous
//
#include <hip/hip_runtime.h>
#include <hip/hip_bf16.h>
#include <math.h>

#define Bz 16
#define Nz 1024
#define Mz 4
#define Dz 128
#define Hz 4
#define VOCABz 32000
#define CAP 128
#define BNc (Bz * Nz)
#define NC 576            // 512 Wh cols (e*4+h) + 8 f-cols + 56 pad

typedef __attribute__((ext_vector_type(8))) short s16x8;
typedef __attribute__((ext_vector_type(8))) _Float16 f16x8;
typedef __attribute__((ext_vector_type(4))) float f32x4;
typedef __attribute__((ext_vector_type(2))) _Float16 f16x2;

#if defined(__has_builtin)
#if __has_builtin(__builtin_amdgcn_fdot2)
#define FDOT2(w, s, acc) acc = __builtin_amdgcn_fdot2((w), (s), (acc), false)
#endif
#endif
#ifndef FDOT2
#define FDOT2(w, s, acc) acc += (float)(w)[0] * (float)(s)[0] + (float)(w)[1] * (float)(s)[1]
#endif
#define BC16(x) __builtin_bit_cast(f16x2, (x))

__device__ inline unsigned short f32_to_f16_bits(float x) {
    _Float16 hv = (_Float16)x;
    return __builtin_bit_cast(unsigned short, hv);
}
__device__ inline unsigned pack_f16(float a, float b) {
    f16x2 p;
    p[0] = (_Float16)a;
    p[1] = (_Float16)b;
    return __builtin_bit_cast(unsigned, p);
}

// ---------------- prep: CSR (blocks <BNc) + Wcat f16 (1152 blocks) + uinit ----------------
// Wcat[hop][c][d]: c<512 -> W[hop][h=c&3][d][e=c>>2]; c in [512,520): q=c-512,
//   col = sum_e W[hop][h=q&3][d][e] * a[hop][h][(q>>2)*128+e]; c>=520 -> 0.
__global__ __launch_bounds__(256) void k_prep(const float* __restrict__ adj,
                                              const int* __restrict__ kb_len,
                                              const int* __restrict__ conv_len,
                                              const float* __restrict__ gat_W,
                                              const float* __restrict__ gat_a,
                                              const float* __restrict__ hidden,
                                              int* __restrict__ idx, int* __restrict__ cnt,
                                              unsigned short* __restrict__ wt,
                                              float* __restrict__ u) {
    int blk = blockIdx.x;
    int t = threadIdx.x;
    if (blk < BNc) {                      // CSR row
        int row = blk;
        int b = row >> 10, n = row & 1023;
        __shared__ int scnt;
        if (t == 0) scnt = 0;
        __syncthreads();
        int ctx = kb_len[b] + conv_len[b];
        const float4 av = *((const float4*)(adj + (size_t)row * Nz) + t);
        int m0 = t * 4;
#pragma unroll
        for (int k = 0; k < 4; k++) {
            float a = k == 0 ? av.x : k == 1 ? av.y : k == 2 ? av.z : av.w;
            int m = m0 + k;
            bool on = (a > 0.f) || (m == n && n >= ctx);
            if (on) {
                int p = atomicAdd(&scnt, 1);
                if (p < CAP) idx[(size_t)row * CAP + p] = m;
            }
        }
        __syncthreads();
        if (t == 0) cnt[row] = scnt < CAP ? scnt : CAP;
    } else if (blk < BNc + 1152) {        // Wcat: 4*576*128 elems
        int i = (blk - BNc) * 256 + t;
        int d = i & 127;
        int rest = i >> 7;                // hop*576 + c
        int c = rest % NC;
        int hop = rest / NC;
        float v;
        if (c < 512) {
            int h = c & 3, e = c >> 2;
            v = gat_W[(((size_t)(hop * 4 + h)) * 128 + d) * 128 + e];
        } else if (c < 520) {
            int q = c - 512;
            int h = q & 3, which = q >> 2;
            const float* wrow = gat_W + (((size_t)(hop * 4 + h)) * 128 + d) * 128;
            const float* arow = gat_a + ((size_t)(hop * 4 + h)) * 256 + which * 128;
            float s = 0.f;
            for (int e = 0; e < 128; e++) s += wrow[e] * arow[e];
            v = s;
        } else {
            v = 0.f;
        }
        wt[i] = f32_to_f16_bits(v);
    } else {                              // u init
        int i = (blk - BNc - 1152) * 256 + t;
        if (i < Bz * Dz) u[i] = hidden[i];
    }
}

// ---------------- embed all 4 hops: x = sum emb rows (+ dh), store f16 --------------------
__global__ __launch_bounds__(128) void k_embed4(const int* __restrict__ story,
                                                const float* __restrict__ emb,
                                                const float* __restrict__ dh,
                                                const int* __restrict__ kb_len,
                                                const int* __restrict__ conv_len,
                                                unsigned short* __restrict__ xhi) {
    int row = blockIdx.x;                 // b*N + n
    int b = row >> 10, n = row & 1023;
    int d = threadIdx.x;                  // 128
    const int* st = story + (size_t)row * Mz;
    int s0 = st[0], s1 = st[1], s2 = st[2], s3 = st[3];
    int rel = n - (kb_len[b] - 1);
    float dhv = (rel >= 0 && rel < conv_len[b]) ? dh[((size_t)(b << 10) + rel) * Dz + d] : 0.f;
#pragma unroll
    for (int hop = 0; hop < 4; hop++) {
        const float* ek = emb + (size_t)hop * VOCABz * Dz;
        float acc = ek[(size_t)s0 * Dz + d] + ek[(size_t)s1 * Dz + d]
                  + ek[(size_t)s2 * Dz + d] + ek[(size_t)s3 * Dz + d] + dhv;
        xhi[(size_t)hop * BNc * Dz + (size_t)row * Dz + d] = f32_to_f16_bits(acc);
    }
}

// ---------------- GEMM X@Wcat (f16 MFMA): WhT f16 [hop][row][c], ff fp32 [hop][row][8] ----
#define AST 72
__global__ __launch_bounds__(256) void k_whf4(const unsigned short* __restrict__ xhi_a,
                                              const unsigned short* __restrict__ wt_a,
                                              unsigned short* __restrict__ WhT_a,
                                              float* __restrict__ ff) {
    int blk = blockIdx.x;
    int xcd = blk & 7;
    int s = blk >> 3;
    int hop = s / 144;
    int r = s - hop * 144;
    int rt = r / 9;
    int ct = r - rt * 9;
    int row0 = (xcd * 16 + rt) * 128;
    int t = threadIdx.x;
    int wave = t >> 6, lane = t & 63;
    int quad = lane >> 4, l16 = lane & 15;

    const unsigned short* xhi = xhi_a + (size_t)hop * BNc * Dz;
    const unsigned short* wt = wt_a + (size_t)hop * NC * 128;

    __shared__ unsigned short Ah[128 * AST];   // X tile [r][k]
    __shared__ unsigned short Bh[64 * AST];    // Wcat tile [c][d]

    f32x4 acc[2][4];
#pragma unroll
    for (int mt = 0; mt < 2; mt++)
#pragma unroll
        for (int nt = 0; nt < 4; nt++) acc[mt][nt] = (f32x4)0.f;

    for (int ph = 0; ph < 2; ph++) {
        int kb = ph * 64;
        for (int i = t; i < 1024; i += 256) {
            int rr = i >> 3, c = (i & 7) * 8;
            *(uint4*)&Ah[rr * AST + c] = *(const uint4*)&xhi[(size_t)(row0 + rr) * Dz + kb + c];
        }
        for (int i = t; i < 512; i += 256) {
            int cr = i >> 3, cc = (i & 7) * 8;
            *(uint4*)&Bh[cr * AST + cc] =
                *(const uint4*)&wt[((size_t)(ct * 64 + cr)) * 128 + kb + cc];
        }
        __syncthreads();
#pragma unroll
        for (int ks = 0; ks < 2; ks++) {
            int ko = ks * 32 + quad * 8;
            f16x8 ah[2];
#pragma unroll
            for (int mt = 0; mt < 2; mt++) {
                int rr = wave * 32 + mt * 16 + l16;
                ah[mt] = __builtin_bit_cast(f16x8, *(const s16x8*)&Ah[rr * AST + ko]);
            }
#pragma unroll
            for (int nt = 0; nt < 4; nt++) {
                int cc = nt * 16 + l16;
                f16x8 bh = __builtin_bit_cast(f16x8, *(const s16x8*)&Bh[cc * AST + ko]);
#pragma unroll
                for (int mt = 0; mt < 2; mt++)
                    acc[mt][nt] = __builtin_amdgcn_mfma_f32_16x16x32_f16(ah[mt], bh, acc[mt][nt], 0, 0, 0);
            }
        }
        __syncthreads();
    }

    if (ct < 8) {
        // repack 128x64 f16 tile through LDS (alias Ah), then coalesced uint4 stores
        unsigned short* St = Ah;
#pragma unroll
        for (int mt = 0; mt < 2; mt++)
#pragma unroll
            for (int nt = 0; nt < 4; nt++)
#pragma unroll
                for (int reg = 0; reg < 4; reg++) {
                    int rr = wave * 32 + mt * 16 + quad * 4 + reg;
                    int cc = nt * 16 + l16;
                    St[rr * AST + cc] = f32_to_f16_bits(acc[mt][nt][reg]);
                }
        __syncthreads();
        int rr = t >> 1, seg = t & 1;
        size_t gbase = ((size_t)hop * BNc + row0 + rr) * 512 + ct * 64 + seg * 32;
#pragma unroll
        for (int k = 0; k < 4; k++) {
            uint4 vv = *(uint4*)&St[rr * AST + seg * 32 + k * 8];
            *(uint4*)&WhT_a[gbase + k * 8] = vv;
        }
    } else {
        if (l16 < 8) {
#pragma unroll
            for (int mt = 0; mt < 2; mt++)
#pragma unroll
                for (int reg = 0; reg < 4; reg++) {
                    int row = row0 + wave * 32 + mt * 16 + quad * 4 + reg;
                    ff[((size_t)hop * BNc + row) * 8 + l16] = acc[mt][0][reg];
                }
        }
    }
}

// ---------------- full-wave single-row attention (fallback: deg>32 or deg==0) -------------
__device__ void attn_row_full(const unsigned short* __restrict__ WhTb,
                              const float* __restrict__ ffh,
                              const int* __restrict__ idx, int deg, int b, int row,
                              int lane, float* __restrict__ Gp) {
    const char* wblc = (const char*)WhTb + lane * 16;
    float accx = 0.f, accy = 0.f;
    if (deg > 0) {
        int m0 = lane < deg ? idx[(size_t)row * CAP + lane] : -1;
        int m1 = lane + 64 < deg ? idx[(size_t)row * CAP + lane + 64] : -1;
        float4 f1r = *(const float4*)&ffh[(size_t)row * 8];
        int m0c = m0 < 0 ? 0 : m0, m1c = m1 < 0 ? 0 : m1;
        float4 f2a = *(const float4*)&ffh[((size_t)(b << 10) + m0c) * 8 + 4];
        float4 f2b = *(const float4*)&ffh[((size_t)(b << 10) + m1c) * 8 + 4];
        float e0[4], e1[4];
        e0[0] = f1r.x + f2a.x; e0[1] = f1r.y + f2a.y; e0[2] = f1r.z + f2a.z; e0[3] = f1r.w + f2a.w;
        e1[0] = f1r.x + f2b.x; e1[1] = f1r.y + f2b.y; e1[2] = f1r.z + f2b.z; e1[3] = f1r.w + f2b.w;
#pragma unroll
        for (int h = 0; h < 4; h++) {
            e0[h] = e0[h] >= 0.f ? e0[h] : 0.2f * e0[h];
            e1[h] = e1[h] >= 0.f ? e1[h] : 0.2f * e1[h];
            if (m0 < 0) e0[h] = -1e30f;
            if (m1 < 0) e1[h] = -1e30f;
        }
        float w0[4], w1[4];
#pragma unroll
        for (int h = 0; h < 4; h++) {
            float m = fmaxf(e0[h], e1[h]);
#pragma unroll
            for (int mm = 1; mm < 64; mm <<= 1) m = fmaxf(m, __shfl_xor(m, mm));
            w0[h] = expf(e0[h] - m);
            w1[h] = expf(e1[h] - m);
            float sm = w0[h] + w1[h];
#pragma unroll
            for (int mm = 1; mm < 64; mm <<= 1) sm += __shfl_xor(sm, mm);
            float inv = 0.25f / sm;
            w0[h] *= inv;
            w1[h] *= inv;
        }
        unsigned w01_0 = pack_f16(w0[0], w0[1]), w23_0 = pack_f16(w0[2], w0[3]);
        unsigned w01_1 = pack_f16(w1[0], w1[1]), w23_1 = pack_f16(w1[2], w1[3]);
        int moff0 = m0c << 10;
        int moff1 = m1c << 10;
        int dlo = deg < 64 ? deg : 64;
#pragma unroll 2
        for (int j = 0; j < dlo; j++) {
            int so = __builtin_amdgcn_readlane(moff0, j);
            unsigned a01 = (unsigned)__builtin_amdgcn_readlane((int)w01_0, j);
            unsigned a23 = (unsigned)__builtin_amdgcn_readlane((int)w23_0, j);
            uint4 raw = *(const uint4*)(wblc + so);
            f16x2 p01 = BC16(a01), p23 = BC16(a23);
            FDOT2(BC16(raw.x), p01, accx);
            FDOT2(BC16(raw.y), p23, accx);
            FDOT2(BC16(raw.z), p01, accy);
            FDOT2(BC16(raw.w), p23, accy);
        }
        for (int j = 0; j < deg - 64; j++) {
            int so = __builtin_amdgcn_readlane(moff1, j);
            unsigned a01 = (unsigned)__builtin_amdgcn_readlane((int)w01_1, j);
            unsigned a23 = (unsigned)__builtin_amdgcn_readlane((int)w23_1, j);
            uint4 raw = *(const uint4*)(wblc + so);
            f16x2 p01 = BC16(a01), p23 = BC16(a23);
            FDOT2(BC16(raw.x), p01, accx);
            FDOT2(BC16(raw.y), p23, accx);
            FDOT2(BC16(raw.z), p01, accy);
            FDOT2(BC16(raw.w), p23, accy);
        }
    } else {
        // all-masked row: softmax of constant -9e15 = uniform 1/N over ALL m (JAX semantics)
        for (int m = 0; m < Nz; m++) {
            uint4 raw = *(const uint4*)(wblc + (m << 10));
            accx += (float)BC16(raw.x)[0] + (float)BC16(raw.x)[1]
                  + (float)BC16(raw.y)[0] + (float)BC16(raw.y)[1];
            accy += (float)BC16(raw.z)[0] + (float)BC16(raw.z)[1]
                  + (float)BC16(raw.w)[0] + (float)BC16(raw.w)[1];
        }
        accx *= 1.f / (Hz * Nz);
        accy *= 1.f / (Hz * Nz);
    }
    *(float2*)&Gp[lane * 2] = make_float2(accx, accy);
}

// ---------------- sparse GAT attention: TWO rows per wave (32-lane halves) ----------------
// pair-per-XCD swizzle preserved. Fast path (both degs in [1,32]): j-loop unrolled 4x to
// keep 8 loads + 12 shfls in flight (latency was the R9 limiter).
__global__ __launch_bounds__(256) void k_attn4(const unsigned short* __restrict__ WhT_a,
                                               const float* __restrict__ ff,
                                               const int* __restrict__ idx,
                                               const int* __restrict__ cnt,
                                               float* __restrict__ G_a) {
    int blk = blockIdx.x;                 // 8192 blocks
    int xcd = blk & 7;
    int s = blk >> 3;                     // 0..1023
    int g = s >> 7;                       // 0..7
    int p = (g << 3) | xcd;               // pair 0..63
    int hop = p >> 4, b = p & 15;
    int wid = threadIdx.x >> 6, lane = threadIdx.x & 63;
    int r2 = ((s & 127) << 2) | wid;      // row-pair 0..511
    int half = lane >> 5, l32 = lane & 31;
    int n = (r2 << 1) | half;
    int row = (b << 10) | n;
    const unsigned short* WhTb = WhT_a + ((size_t)hop * BNc + ((size_t)b << 10)) * 512;
    const float* ffh = ff + (size_t)hop * BNc * 8;
    int deg = cnt[row];
    int deg0 = __shfl(deg, 0), deg1 = __shfl(deg, 32);
    if (deg0 > 0 && deg1 > 0 && deg0 <= 32 && deg1 <= 32) {
        int m = l32 < deg ? idx[(size_t)row * CAP + l32] : -1;
        int mc = m < 0 ? 0 : m;
        float4 f1r = *(const float4*)&ffh[(size_t)row * 8];
        float4 f2m = *(const float4*)&ffh[((size_t)(b << 10) + mc) * 8 + 4];
        float e[4];
        e[0] = f1r.x + f2m.x; e[1] = f1r.y + f2m.y; e[2] = f1r.z + f2m.z; e[3] = f1r.w + f2m.w;
        float w[4];
#pragma unroll
        for (int h = 0; h < 4; h++) {
            e[h] = e[h] >= 0.f ? e[h] : 0.2f * e[h];
            if (m < 0) e[h] = -1e30f;
        }
#pragma unroll
        for (int h = 0; h < 4; h++) {
            float mx = e[h];
#pragma unroll
            for (int mm = 1; mm < 32; mm <<= 1) mx = fmaxf(mx, __shfl_xor(mx, mm));
            w[h] = expf(e[h] - mx);
            float sm = w[h];
#pragma unroll
            for (int mm = 1; mm < 32; mm <<= 1) sm += __shfl_xor(sm, mm);
            w[h] *= 0.25f / sm;
        }
        int w01 = (int)pack_f16(w[0], w[1]);
        int w23 = (int)pack_f16(w[2], w[3]);
        int moff = mc << 10;
        int dmax = deg0 > deg1 ? deg0 : deg1;
        int srcbase = lane & 32;
        const char* wbl = (const char*)WhTb + l32 * 32;   // this lane's 16 cols
        float a0 = 0.f, a1 = 0.f, a2 = 0.f, a3 = 0.f;
#pragma unroll 4
        for (int j = 0; j < dmax; j++) {
            int src = srcbase + j;
            int vo = __shfl(moff, src);
            unsigned b01 = (unsigned)__shfl(w01, src);
            unsigned b23 = (unsigned)__shfl(w23, src);
            uint4 r0 = *(const uint4*)(wbl + vo);
            uint4 r1 = *(const uint4*)(wbl + vo + 16);
            f16x2 p01 = BC16(b01), p23 = BC16(b23);
            FDOT2(BC16(r0.x), p01, a0);
            FDOT2(BC16(r0.y), p23, a0);
            FDOT2(BC16(r0.z), p01, a1);
            FDOT2(BC16(r0.w), p23, a1);
            FDOT2(BC16(r1.x), p01, a2);
            FDOT2(BC16(r1.y), p23, a2);
            FDOT2(BC16(r1.z), p01, a3);
            FDOT2(BC16(r1.w), p23, a3);
        }
        *(float4*)&G_a[((size_t)hop * BNc + row) * Dz + l32 * 4] = make_float4(a0, a1, a2, a3);
    } else {
        int row0 = (b << 10) | (r2 << 1);
        attn_row_full(WhTb, ffh, idx, deg0, b, row0, lane,
                      &G_a[((size_t)hop * BNc + row0) * Dz]);
        attn_row_full(WhTb, ffh, idx, deg1, b, row0 + 1, lane,
                      &G_a[((size_t)hop * BNc + row0 + 1) * Dz]);
    }
}

// ---------------- logits: one wave per row, 4 rows per block ------------------------------
__global__ __launch_bounds__(256) void k_logits4(const float* __restrict__ G_a, int hopA,
                                                 const float* __restrict__ u,
                                                 float* __restrict__ logits) {
    int row = blockIdx.x * 4 + (threadIdx.x >> 6);
    int lane = threadIdx.x & 63;
    int b = row >> 10;
    const float* g = G_a + ((size_t)hopA * BNc + row) * Dz;
    const float* ub = u + b * Dz;
    float s = g[lane] * ub[lane] + g[lane + 64] * ub[lane + 64];
#pragma unroll
    for (int off = 32; off; off >>= 1) s += __shfl_down(s, off);
    if (lane == 0) logits[row] = s;
}

// ---------------- u update: 8 blocks per batch, redundant softmax stats -------------------
__global__ __launch_bounds__(256) void k_upd(const float* __restrict__ G_a, int hopC,
                                             const float* __restrict__ logits,
                                             float* __restrict__ u) {
    int b = blockIdx.x >> 3;
    int chunk = blockIdx.x & 7;
    int t = threadIdx.x;                  // 256
    __shared__ float sp[1024];
    __shared__ float red[10];
    __shared__ float part[2][128];
    const float* l = logits + (size_t)b * Nz;
    float4 lv = *((const float4*)l + t);
    float mx = fmaxf(fmaxf(lv.x, lv.y), fmaxf(lv.z, lv.w));
#pragma unroll
    for (int mm = 1; mm < 64; mm <<= 1) mx = fmaxf(mx, __shfl_xor(mx, mm));
    if ((t & 63) == 0) red[t >> 6] = mx;
    __syncthreads();
    if (t == 0) {
        float m = red[0];
        for (int i = 1; i < 4; i++) m = fmaxf(m, red[i]);
        red[8] = m;
    }
    __syncthreads();
    mx = red[8];
    float e0 = expf(lv.x - mx), e1 = expf(lv.y - mx), e2 = expf(lv.z - mx), e3 = expf(lv.w - mx);
    float sum = e0 + e1 + e2 + e3;
#pragma unroll
    for (int mm = 1; mm < 64; mm <<= 1) sum += __shfl_xor(sum, mm);
    if ((t & 63) == 0) red[4 + (t >> 6)] = sum;
    __syncthreads();
    if (t == 0) {
        float ss = 0.f;
        for (int i = 0; i < 4; i++) ss += red[4 + i];
        red[9] = 1.f / ss;
    }
    __syncthreads();
    float inv = red[9];
    sp[t * 4] = e0 * inv;
    sp[t * 4 + 1] = e1 * inv;
    sp[t * 4 + 2] = e2 * inv;
    sp[t * 4 + 3] = e3 * inv;
    __syncthreads();
    int d = t & 127, half = t >> 7;
    const float* gc = G_a + ((size_t)hopC * BNc + (b << 10) + chunk * 128 + half * 64) * Dz + d;
    const float* pc = &sp[chunk * 128 + half * 64];
    float acc = 0.f;
#pragma unroll 4
    for (int j = 0; j < 64; j++) acc += gc[(size_t)j * Dz] * pc[j];
    part[half][d] = acc;
    __syncthreads();
    if (t < 128) atomicAdd(&u[b * Dz + t], part[0][t] + part[1][t]);
}

// ---------------- final out: sigmoid(logits), u, logits -----------------------------------
__global__ void k_fin(const float* __restrict__ logits, const float* __restrict__ u,
                      float* __restrict__ out) {
    int i = blockIdx.x * 256 + threadIdx.x;
    if (i < Bz * Nz) {
        float l = logits[i];
        out[i] = 1.f / (1.f + expf(-l));
        out[Bz * Nz + Bz * Dz + i] = l;
    }
    if (i < Bz * Dz) out[Bz * Nz + i] = u[i];
}

// ---------------- host ---------------------------------------------------------------------
extern "C" void kernel_launch(void* const* d_in, const int* in_sizes, int n_in,
                              void* d_out, int out_size, void* d_ws, size_t ws_size,
                              hipStream_t stream) {
    const int*   story    = (const int*)d_in[0];
    const int*   kb_len   = (const int*)d_in[1];
    const int*   conv_len = (const int*)d_in[2];
    const float* hidden   = (const float*)d_in[3];
    const float* dh       = (const float*)d_in[4];
    const float* adj      = (const float*)d_in[5];
    const float* emb      = (const float*)d_in[6];
    const float* gat_W    = (const float*)d_in[7];
    const float* gat_a    = (const float*)d_in[8];
    float* out = (float*)d_out;

    char* w = (char*)d_ws;
    auto alloc = [&](size_t bytes) {
        char* pp = w;
        w += (bytes + 255) & ~(size_t)255;
        return pp;
    };
    const size_t BN = (size_t)Bz * Nz;
    int*            idx  = (int*)           alloc(BN * CAP * 4);          // 8.4 MB
    int*            cnt  = (int*)           alloc(BN * 4);
    unsigned short* xhi  = (unsigned short*)alloc(4 * BN * Dz * 2);       // 16.8 MB
    unsigned short* wt   = (unsigned short*)alloc(4 * NC * 128 * 2);      // 0.6 MB
    unsigned short* WhT  = (unsigned short*)alloc(4 * BN * 512 * 2);      // 67 MB
    float*          ff   = (float*)         alloc(4 * BN * 8 * 4);        // 2.1 MB
    float*          G    = (float*)         alloc(4 * BN * Dz * 4);       // 33.6 MB
    float*          logits = (float*)       alloc(BN * 4);
    float*          u    = (float*)         alloc((size_t)Bz * Dz * 4);

    k_prep<<<BNc + 1152 + 8, 256, 0, stream>>>(adj, kb_len, conv_len, gat_W, gat_a, hidden,
                                               idx, cnt, wt, u);
    k_embed4<<<BNc, 128, 0, stream>>>(story, emb, dh, kb_len, conv_len, xhi);
    k_whf4<<<4608, 256, 0, stream>>>(xhi, wt, WhT, ff);
    k_attn4<<<8192, 256, 0, stream>>>(WhT, ff, idx, cnt, G);
    for (int hop = 0; hop < 3; hop++) {
        k_logits4<<<BNc / 4, 256, 0, stream>>>(G, hop, u, logits);
        k_upd<<<Bz * 8, 256, 0, stream>>>(G, hop + 1, logits, u);
    }
    k_fin<<<(Bz * Nz + 255) / 256, 256, 0, stream>>>(logits, u, out);
}